// Round 10
// baseline (351.646 us; speedup 1.0000x reference)
//
#include <hip/hip_runtime.h>
#include <hip/hip_bf16.h>

#define N_NODES 50000
#define N_EDGES 800000
#define NNZ_H   800000
#define M_HE    10000
#define F_IN    128
#define F_HID   64

// coarse-bucket geometry for the two-level counting sort
#define SH_E 7
#define NB_E ((N_NODES + 127) >> 7)     // 391
#define SH_H 5
#define NB_H ((M_HE + 31) >> 5)         // 313
#define SH_N 7
#define NB_N ((N_NODES + 127) >> 7)     // 391
#define TILE 4096
#define GB   ((N_EDGES + TILE - 1) / TILE)   // 196 (E == NNZ)
#define NBMAX 400
#define KPBMAX 128
#define GG  782     // (N_NODES+63)/64 GEMM blocks
#define GWN 12500   // N_NODES/4 wave-per-node blocks

// ---------------- pass A: fused bucket histograms (LDS pre-aggregated) ----------------
__global__ void k_hist_all(const int* __restrict__ e_col, const int* __restrict__ h_idx,
                           const int* __restrict__ n_idx,
                           int* __restrict__ bcntE, int* __restrict__ bcntH, int* __restrict__ bcntN) {
    __shared__ int hE[NB_E], hH[NB_H], hN[NB_N];
    for (int i = threadIdx.x; i < NB_E; i += 256) hE[i] = 0;
    for (int i = threadIdx.x; i < NB_H; i += 256) hH[i] = 0;
    for (int i = threadIdx.x; i < NB_N; i += 256) hN[i] = 0;
    __syncthreads();
    int stride = gridDim.x * 256;
    for (int i = blockIdx.x * 256 + threadIdx.x; i < N_EDGES; i += stride) {
        atomicAdd(&hE[e_col[i] >> SH_E], 1);
        atomicAdd(&hH[h_idx[i] >> SH_H], 1);
        atomicAdd(&hN[n_idx[i] >> SH_N], 1);
    }
    __syncthreads();
    for (int i = threadIdx.x; i < NB_E; i += 256) if (hE[i]) atomicAdd(&bcntE[i], hE[i]);
    for (int i = threadIdx.x; i < NB_H; i += 256) if (hH[i]) atomicAdd(&bcntH[i], hH[i]);
    for (int i = threadIdx.x; i < NB_N; i += 256) if (hN[i]) atomicAdd(&bcntN[i], hN[i]);
}

// ---------------- block-wide exclusive scan helper ----------------
__device__ void scan_block(const int* __restrict__ in, int* __restrict__ out, int n) {
    __shared__ int s[1024];
    int t = threadIdx.x;
    int chunk = (n + 1023) >> 10;
    int b = t * chunk;
    int e = min(b + chunk, n);
    int sum = 0;
    for (int i = b; i < e; ++i) sum += in[i];
    s[t] = sum;
    __syncthreads();
    for (int d = 1; d < 1024; d <<= 1) {
        int v = (t >= d) ? s[t - d] : 0;
        __syncthreads();
        s[t] += v;
        __syncthreads();
    }
    int run = (t > 0) ? s[t - 1] : 0;
    for (int i = b; i < e; ++i) { int v = in[i]; out[i] = run; run += v; }
}
__global__ void k_scan_buckets(const int* __restrict__ bcntE, int* __restrict__ boffE,
                               const int* __restrict__ bcntH, int* __restrict__ boffH,
                               const int* __restrict__ bcntN, int* __restrict__ boffN) {
    if (blockIdx.x == 0)      scan_block(bcntE, boffE, NB_E);
    else if (blockIdx.x == 1) scan_block(bcntH, boffH, NB_H);
    else                      scan_block(bcntN, boffN, NB_N);
}

// ---------------- pass B: chunked scatter, packed int payload (write-combining) ----------------
__device__ void chunk_scatter(const int* __restrict__ keys, const int* __restrict__ vals,
                              int n, int sh, int nb,
                              const int* __restrict__ boff, int* __restrict__ bcur,
                              int* __restrict__ bk, int blk) {
    __shared__ int h[NBMAX], loc[NBMAX], base[NBMAX], hc[NBMAX];
    __shared__ int buf[TILE];
    __shared__ unsigned short bkt[TILE];
    int t0 = blk * TILE;
    int tend = min(t0 + TILE, n);
    int cnt = tend - t0;
    for (int b = threadIdx.x; b < nb; b += 256) { h[b] = 0; hc[b] = 0; }
    __syncthreads();
    for (int i = t0 + threadIdx.x; i < tend; i += 256)
        atomicAdd(&h[keys[i] >> sh], 1);
    __syncthreads();
    if (threadIdx.x == 0) {
        int run = 0;
        for (int b = 0; b < nb; ++b) { loc[b] = run; run += h[b]; }
    }
    __syncthreads();
    for (int b = threadIdx.x; b < nb; b += 256)
        base[b] = boff[b] + atomicAdd(&bcur[b], h[b]);
    __syncthreads();
    for (int i = t0 + threadIdx.x; i < tend; i += 256) {
        int k = keys[i];
        int b = k >> sh;
        int r = loc[b] + atomicAdd(&hc[b], 1);
        buf[r] = ((k - (b << sh)) << 16) | vals[i];   // lk<=127, val<65536
        bkt[r] = (unsigned short)b;
    }
    __syncthreads();
    for (int j = threadIdx.x; j < cnt; j += 256) {
        int b = bkt[j];
        bk[base[b] + (j - loc[b])] = buf[j];          // contiguous block-owned runs
    }
}
__global__ void k_chunk_all(const int* __restrict__ e_row, const int* __restrict__ e_col,
                            const int* __restrict__ n_idx, const int* __restrict__ h_idx,
                            const int* __restrict__ boffE, int* __restrict__ bcurE, int* __restrict__ bkE,
                            const int* __restrict__ boffH, int* __restrict__ bcurH, int* __restrict__ bkH,
                            const int* __restrict__ boffN, int* __restrict__ bcurN, int* __restrict__ bkN) {
    int gb = blockIdx.x;
    if (gb < GB)            chunk_scatter(e_col, e_row, N_EDGES, SH_E, NB_E, boffE, bcurE, bkE, gb);
    else if (gb < 2 * GB)   chunk_scatter(h_idx, n_idx, NNZ_H,  SH_H, NB_H, boffH, bcurH, bkH, gb - GB);
    else                    chunk_scatter(n_idx, h_idx, NNZ_H,  SH_N, NB_N, boffN, bcurN, bkN, gb - 2 * GB);
}

// ---------------- pass C: per-bucket CSR finalize ----------------
__global__ void k_fin_all(const int* __restrict__ bkE, const int* __restrict__ boffE,
                          int* __restrict__ srtE, int* __restrict__ offE,
                          const int* __restrict__ bkH, const int* __restrict__ boffH,
                          int* __restrict__ srtH, int* __restrict__ offH,
                          const int* __restrict__ bkN, const int* __restrict__ boffN,
                          int* __restrict__ srtN, int* __restrict__ offN) {
    __shared__ int koff[KPBMAX];
    __shared__ int kcur[KPBMAX];
    __shared__ int tsum[256];
    int b = blockIdx.x;
    const int* bk; const int* boff; int* srt; int* off;
    int nb, sh, nkeys, total;
    if (b < NB_E) {
        bk = bkE; boff = boffE; srt = srtE; off = offE;
        nb = NB_E; sh = SH_E; nkeys = N_NODES; total = N_EDGES;
    } else if (b < NB_E + NB_H) {
        b -= NB_E;
        bk = bkH; boff = boffH; srt = srtH; off = offH;
        nb = NB_H; sh = SH_H; nkeys = M_HE; total = NNZ_H;
    } else {
        b -= NB_E + NB_H;
        bk = bkN; boff = boffN; srt = srtN; off = offN;
        nb = NB_N; sh = SH_N; nkeys = N_NODES; total = NNZ_H;
    }
    int kpb = 1 << sh;
    int k0 = b << sh;
    int beg = boff[b];
    int end = (b + 1 < nb) ? boff[b + 1] : total;
    int t = threadIdx.x;
    if (t < kpb) { koff[t] = 0; kcur[t] = 0; }
    __syncthreads();
    for (int i = beg + t; i < end; i += 256)
        atomicAdd(&koff[((unsigned)bk[i]) >> 16], 1);
    __syncthreads();
    int v = (t < kpb) ? koff[t] : 0;
    tsum[t] = v;
    __syncthreads();
    for (int d = 1; d < 256; d <<= 1) {
        int u = (t >= d) ? tsum[t - d] : 0;
        __syncthreads();
        tsum[t] += u;
        __syncthreads();
    }
    if (t < kpb) koff[t] = tsum[t] - v;   // exclusive
    __syncthreads();
    if (t < kpb && (k0 + t) < nkeys) off[k0 + t] = beg + koff[t];
    if (b == nb - 1 && t == 0) off[nkeys] = total;
    for (int i = beg + t; i < end; i += 256) {
        int p = bk[i];
        int lk = ((unsigned)p) >> 16;
        int pos = beg + koff[lk] + atomicAdd(&kcur[lk], 1);
        srt[pos] = p & 0xFFFF;
    }
}

// ---------------- register-tiled GEMM body: 64x64 tile, 4x4/thread ----------------
template<int K, bool SCALE>
__device__ __forceinline__ void gemm_body(const float* __restrict__ xin, const float* __restrict__ w,
                                          const int* __restrict__ offE, float* __restrict__ out,
                                          int blk, float* __restrict__ wl, float* __restrict__ xs) {
    int tid = threadIdx.x;
    int wv = tid >> 6, lane = tid & 63;
    int cg = lane & 15;
    int rg = lane >> 4;
    int rl = wv * 16 + rg * 4;
    int r0 = blk * 64;
    float acc[4][4] = {};
    for (int k0 = 0; k0 < K; k0 += 64) {
        {
            const float4* wsrc = (const float4*)(w + k0 * 64);
            float4* wdst = (float4*)wl;
            for (int j = tid; j < 1024; j += 256) wdst[j] = wsrc[j];
        }
        for (int p = tid; p < 1024; p += 256) {
            int r = p >> 4, c4 = p & 15;
            int row = min(r0 + r, N_NODES - 1);
            float4 vv = *(const float4*)(xin + (size_t)row * K + k0 + 4 * c4);
            *(float4*)&xs[r * 68 + 4 * c4] = vv;
        }
        __syncthreads();
#pragma unroll 4
        for (int kk = 0; kk < 64; ++kk) {
            float4 wf = *(const float4*)&wl[kk * 64 + cg * 4];
            float x0 = xs[(rl + 0) * 68 + kk];
            float x1 = xs[(rl + 1) * 68 + kk];
            float x2 = xs[(rl + 2) * 68 + kk];
            float x3 = xs[(rl + 3) * 68 + kk];
            acc[0][0] += x0 * wf.x; acc[0][1] += x0 * wf.y; acc[0][2] += x0 * wf.z; acc[0][3] += x0 * wf.w;
            acc[1][0] += x1 * wf.x; acc[1][1] += x1 * wf.y; acc[1][2] += x1 * wf.z; acc[1][3] += x1 * wf.w;
            acc[2][0] += x2 * wf.x; acc[2][1] += x2 * wf.y; acc[2][2] += x2 * wf.z; acc[2][3] += x2 * wf.w;
            acc[3][0] += x3 * wf.x; acc[3][1] += x3 * wf.y; acc[3][2] += x3 * wf.z; acc[3][3] += x3 * wf.w;
        }
        __syncthreads();
    }
#pragma unroll
    for (int i = 0; i < 4; ++i) {
        int row = r0 + rl + i;
        if (row < N_NODES) {
            float s = 1.0f;
            if (SCALE) {
                float deg = (float)(offE[row + 1] - offE[row]);
                s = rsqrtf(deg + 1.0f);
            }
            float4 o = make_float4(acc[i][0] * s, acc[i][1] * s, acc[i][2] * s, acc[i][3] * s);
            *(float4*)&out[(size_t)row * 64 + cg * 4] = o;
        }
    }
}

// ---------------- gather bodies ----------------
template<bool ELU>
__device__ __forceinline__ void gcn_gather_body(const int* __restrict__ off, const int* __restrict__ srcs,
                                                const float* __restrict__ xw, const float* __restrict__ b,
                                                float* __restrict__ out, int blk) {
    int wid = blk * 4 + (threadIdx.x >> 6);
    int f = threadIdx.x & 63;
    if (wid >= N_NODES) return;
    int beg = off[wid], end = off[wid + 1];
    float a0 = 0, a1 = 0, a2 = 0, a3 = 0;
    int e = beg;
    for (; e + 4 <= end; e += 4) {
        int s0 = srcs[e], s1 = srcs[e + 1], s2 = srcs[e + 2], s3 = srcs[e + 3];
        a0 += xw[(size_t)s0 * 64 + f];
        a1 += xw[(size_t)s1 * 64 + f];
        a2 += xw[(size_t)s2 * 64 + f];
        a3 += xw[(size_t)s3 * 64 + f];
    }
    for (; e < end; ++e) a0 += xw[(size_t)srcs[e] * 64 + f];
    float acc = (a0 + a1) + (a2 + a3);
    float di = rsqrtf((float)(end - beg) + 1.0f);
    float v = di * (acc + xw[(size_t)wid * 64 + f]) + b[f];
    if (ELU) v = (v > 0.0f) ? v : expm1f(v);
    out[(size_t)wid * 64 + f] = v;
}

__device__ __forceinline__ void he_gather_body(const int* __restrict__ off, const int* __restrict__ nodes,
                                               const float* __restrict__ xw, float* __restrict__ C,
                                               int he, float (*red)[64]) {
    int wv = threadIdx.x >> 6, f = threadIdx.x & 63;
    int beg = off[he], end = off[he + 1];
    int cnt = end - beg;
    int per = (cnt + 3) >> 2;
    int b0 = beg + wv * per;
    int e0 = min(b0 + per, end);
    float a0 = 0, a1 = 0, a2 = 0, a3 = 0;
    int e = b0;
    for (; e + 4 <= e0; e += 4) {
        int s0 = nodes[e], s1 = nodes[e + 1], s2 = nodes[e + 2], s3 = nodes[e + 3];
        a0 += xw[(size_t)s0 * 64 + f];
        a1 += xw[(size_t)s1 * 64 + f];
        a2 += xw[(size_t)s2 * 64 + f];
        a3 += xw[(size_t)s3 * 64 + f];
    }
    for (; e < e0; ++e) a0 += xw[(size_t)nodes[e] * 64 + f];
    red[wv][f] = (a0 + a1) + (a2 + a3);
    __syncthreads();
    if (wv == 0) {
        float tot = (red[0][f] + red[1][f]) + (red[2][f] + red[3][f]);
        float binv = (cnt > 0) ? 1.0f / (float)cnt : 0.0f;
        C[(size_t)he * 64 + f] = binv * tot;
    }
}

template<bool ELU, bool FUSE>
__device__ __forceinline__ void node_gather_body(const int* __restrict__ off, const int* __restrict__ hes,
                                                 const float* __restrict__ C, const float* __restrict__ b,
                                                 float* __restrict__ out,
                                                 const float* __restrict__ xs, const float* __restrict__ gate,
                                                 float* __restrict__ z, int blk) {
    int wid = blk * 4 + (threadIdx.x >> 6);
    int f = threadIdx.x & 63;
    if (wid >= N_NODES) return;
    int beg = off[wid], end = off[wid + 1];
    float a0 = 0, a1 = 0, a2 = 0, a3 = 0;
    int e = beg;
    for (; e + 4 <= end; e += 4) {
        int s0 = hes[e], s1 = hes[e + 1], s2 = hes[e + 2], s3 = hes[e + 3];
        a0 += C[(size_t)s0 * 64 + f];
        a1 += C[(size_t)s1 * 64 + f];
        a2 += C[(size_t)s2 * 64 + f];
        a3 += C[(size_t)s3 * 64 + f];
    }
    for (; e < end; ++e) a0 += C[(size_t)hes[e] * 64 + f];
    float acc = (a0 + a1) + (a2 + a3);
    float dinv = (end > beg) ? 1.0f / (float)(end - beg) : 0.0f;
    float v = dinv * acc + b[f];
    if (ELU) v = (v > 0.0f) ? v : expm1f(v);
    size_t idx = (size_t)wid * 64 + f;
    out[idx] = v;
    if (FUSE) {
        float a = 1.0f / (1.0f + expf(-gate[0]));
        z[idx] = a * xs[idx] + (1.0f - a) * v;
    }
}

// ---------------- fused dual dispatches ----------------
// L1: A = dis.*(x@w1)  ||  B = x@hw1
__global__ void k_l1_dual(const float* __restrict__ x, const float* __restrict__ w1,
                          const float* __restrict__ hw1, const int* __restrict__ offE,
                          float* __restrict__ A, float* __restrict__ B) {
    __shared__ float wl[64 * 64];
    __shared__ float xs[64 * 68];
    if (blockIdx.x < GG) gemm_body<F_IN, true>(x, w1, offE, A, blockIdx.x, wl, xs);
    else                 gemm_body<F_IN, false>(x, hw1, nullptr, B, blockIdx.x - GG, wl, xs);
}

// L2: AGG1 = ELU(gcnGather(A))  ||  C = heGather(B)
__global__ void k_l2_dual(const int* __restrict__ offE, const int* __restrict__ srtE,
                          const float* __restrict__ A, const float* __restrict__ gb1, float* __restrict__ AGG1,
                          const int* __restrict__ offH, const int* __restrict__ srtH,
                          const float* __restrict__ B, float* __restrict__ C) {
    __shared__ float red[4][64];
    if (blockIdx.x < GWN) gcn_gather_body<true>(offE, srtE, A, gb1, AGG1, blockIdx.x);
    else                  he_gather_body(offH, srtH, B, C, blockIdx.x - GWN, red);
}

// L3: A = dis.*(AGG1@w2)  ||  AGG2 = ELU(nodeGather(C))
__global__ void k_l3_dual(const float* __restrict__ AGG1, const float* __restrict__ w2,
                          const int* __restrict__ offE, float* __restrict__ A,
                          const int* __restrict__ offN, const int* __restrict__ srtN,
                          const float* __restrict__ C, const float* __restrict__ hb1, float* __restrict__ AGG2) {
    __shared__ float wl[64 * 64];
    __shared__ float xs[64 * 68];
    if (blockIdx.x < GG) gemm_body<F_HID, true>(AGG1, w2, offE, A, blockIdx.x, wl, xs);
    else node_gather_body<true, false>(offN, srtN, C, hb1, AGG2, nullptr, nullptr, nullptr, blockIdx.x - GG);
}

// L4: B = AGG2@hw2  ||  xs_out = gcnGather(A)
__global__ void k_l4_dual(const float* __restrict__ AGG2, const float* __restrict__ hw2, float* __restrict__ B,
                          const int* __restrict__ offE, const int* __restrict__ srtE,
                          const float* __restrict__ A, const float* __restrict__ gb2, float* __restrict__ xs_out) {
    __shared__ float wl[64 * 64];
    __shared__ float xs[64 * 68];
    if (blockIdx.x < GG) gemm_body<F_HID, false>(AGG2, hw2, nullptr, B, blockIdx.x, wl, xs);
    else gcn_gather_body<false>(offE, srtE, A, gb2, xs_out, blockIdx.x - GG);
}

// L5: C = heGather(B)
__global__ void k_l5(const int* __restrict__ offH, const int* __restrict__ srtH,
                     const float* __restrict__ B, float* __restrict__ C) {
    __shared__ float red[4][64];
    he_gather_body(offH, srtH, B, C, blockIdx.x, red);
}

// L6: xd_out = nodeGather(C) ; z = a*xs + (1-a)*xd
__global__ void k_l6(const int* __restrict__ offN, const int* __restrict__ srtN,
                     const float* __restrict__ C, const float* __restrict__ hb2, float* __restrict__ xd_out,
                     const float* __restrict__ xs, const float* __restrict__ gate, float* __restrict__ z) {
    node_gather_body<false, true>(offN, srtN, C, hb2, xd_out, xs, gate, z, blockIdx.x);
}

extern "C" void kernel_launch(void* const* d_in, const int* in_sizes, int n_in,
                              void* d_out, int out_size, void* d_ws, size_t ws_size,
                              hipStream_t stream) {
    const float* x      = (const float*)d_in[0];
    const int*   ei     = (const int*)d_in[1];
    const int*   hei    = (const int*)d_in[2];
    const float* gcn1_w = (const float*)d_in[3];
    const float* gcn1_b = (const float*)d_in[4];
    const float* gcn2_w = (const float*)d_in[5];
    const float* gcn2_b = (const float*)d_in[6];
    const float* hyp1_w = (const float*)d_in[7];
    const float* hyp1_b = (const float*)d_in[8];
    const float* hyp2_w = (const float*)d_in[9];
    const float* hyp2_b = (const float*)d_in[10];
    const float* gate   = (const float*)d_in[11];
    float* out = (float*)d_out;

    const int* e_row = ei;               // sources
    const int* e_col = ei + N_EDGES;     // targets
    const int* n_idx = hei;              // node ids
    const int* h_idx = hei + NNZ_H;      // hyperedge ids

    const size_t NV = (size_t)N_NODES * 64;
    float* z_out  = out;
    float* xs_out = out + NV;
    float* xd_out = out + 2 * NV;

    // ---- workspace layout (~64 MB of the 256 MiB ws) ----
    float* A    = (float*)d_ws;          // N*64 (A1 then A2)
    float* B    = A + NV;                // N*64 (B1 then B2)
    float* AGG1 = B + NV;                // N*64
    float* AGG2 = AGG1 + NV;             // N*64
    float* C    = AGG2 + NV;             // M*64 (C1 then C2)
    int* srtE = (int*)(C + (size_t)M_HE * 64);  // E
    int* srtH = srtE + N_EDGES;          // NNZ
    int* srtN = srtH + NNZ_H;            // NNZ
    int* offE = srtN + NNZ_H;            // N+1
    int* offH = offE + (N_NODES + 1);    // M+1
    int* offN = offH + (M_HE + 1);       // N+1
    // contiguous zero block: bucket counts + cursors
    int* bcntE = offN + (N_NODES + 1);   // NB_E
    int* bcntH = bcntE + NB_E;           // NB_H
    int* bcntN = bcntH + NB_H;           // NB_N
    int* bcurE = bcntN + NB_N;           // NB_E
    int* bcurH = bcurE + NB_E;           // NB_H
    int* bcurN = bcurH + NB_H;           // NB_N
    // scan outputs
    int* boffE = bcurN + NB_N;           // NB_E
    int* boffH = boffE + NB_E;           // NB_H
    int* boffN = boffH + NB_H;           // NB_N
    const size_t zero_ints = 2 * (size_t)(NB_E + NB_H + NB_N);
    // packed sort staging aliases A/B (dead during CSR build)
    int* bkE = (int*)A;                  // 3.2 MB
    int* bkH = (int*)B;                  // 3.2 MB
    int* bkN = (int*)AGG1;               // 3.2 MB

    const int BLK = 256;

    // ---- CSR build ----
    hipMemsetAsync(bcntE, 0, zero_ints * sizeof(int), stream);
    k_hist_all<<<256, BLK, 0, stream>>>(e_col, h_idx, n_idx, bcntE, bcntH, bcntN);
    k_scan_buckets<<<3, 1024, 0, stream>>>(bcntE, boffE, bcntH, boffH, bcntN, boffN);
    k_chunk_all<<<3 * GB, BLK, 0, stream>>>(e_row, e_col, n_idx, h_idx,
                                            boffE, bcurE, bkE,
                                            boffH, bcurH, bkH,
                                            boffN, bcurN, bkN);
    k_fin_all<<<NB_E + NB_H + NB_N, BLK, 0, stream>>>(bkE, boffE, srtE, offE,
                                                      bkH, boffH, srtH, offH,
                                                      bkN, boffN, srtN, offN);

    // ---- fused compute chain ----
    k_l1_dual<<<2 * GG, BLK, 0, stream>>>(x, gcn1_w, hyp1_w, offE, A, B);
    k_l2_dual<<<GWN + M_HE, BLK, 0, stream>>>(offE, srtE, A, gcn1_b, AGG1,
                                              offH, srtH, B, C);
    k_l3_dual<<<GG + GWN, BLK, 0, stream>>>(AGG1, gcn2_w, offE, A,
                                            offN, srtN, C, hyp1_b, AGG2);
    k_l4_dual<<<GG + GWN, BLK, 0, stream>>>(AGG2, hyp2_w, B,
                                            offE, srtE, A, gcn2_b, xs_out);
    k_l5<<<M_HE, BLK, 0, stream>>>(offH, srtH, B, C);
    k_l6<<<GWN, BLK, 0, stream>>>(offN, srtN, C, hyp2_b, xd_out, xs_out, gate, z_out);

    (void)in_sizes; (void)n_in; (void)out_size; (void)ws_size;
}

// Round 11
// 322.603 us; speedup vs baseline: 1.0900x; 1.0900x over previous
//
#include <hip/hip_runtime.h>
#include <hip/hip_bf16.h>

#define N_NODES 50000
#define N_EDGES 800000
#define NNZ_H   800000
#define M_HE    10000
#define F_IN    128
#define F_HID   64

// coarse-bucket geometry for the two-level counting sort
#define SH_E 7
#define NB_E ((N_NODES + 127) >> 7)     // 391
#define SH_H 5
#define NB_H ((M_HE + 31) >> 5)         // 313
#define SH_N 7
#define NB_N ((N_NODES + 127) >> 7)     // 391
#define TILE 4096
#define GB   ((N_EDGES + TILE - 1) / TILE)   // 196 (E == NNZ)
#define NBMAX 400
#define KPBMAX 128
#define GG  782     // (N_NODES+63)/64 GEMM blocks
#define GWN 12500   // N_NODES/4 wave-per-node blocks

static __device__ __forceinline__ float bf2f(__hip_bfloat16 v) { return __bfloat162float(v); }

// ---------------- pass A: fused bucket histograms (LDS pre-aggregated) ----------------
__global__ void k_hist_all(const int* __restrict__ e_col, const int* __restrict__ h_idx,
                           const int* __restrict__ n_idx,
                           int* __restrict__ bcntE, int* __restrict__ bcntH, int* __restrict__ bcntN) {
    __shared__ int hE[NB_E], hH[NB_H], hN[NB_N];
    for (int i = threadIdx.x; i < NB_E; i += 256) hE[i] = 0;
    for (int i = threadIdx.x; i < NB_H; i += 256) hH[i] = 0;
    for (int i = threadIdx.x; i < NB_N; i += 256) hN[i] = 0;
    __syncthreads();
    int stride = gridDim.x * 256;
    for (int i = blockIdx.x * 256 + threadIdx.x; i < N_EDGES; i += stride) {
        atomicAdd(&hE[e_col[i] >> SH_E], 1);
        atomicAdd(&hH[h_idx[i] >> SH_H], 1);
        atomicAdd(&hN[n_idx[i] >> SH_N], 1);
    }
    __syncthreads();
    for (int i = threadIdx.x; i < NB_E; i += 256) if (hE[i]) atomicAdd(&bcntE[i], hE[i]);
    for (int i = threadIdx.x; i < NB_H; i += 256) if (hH[i]) atomicAdd(&bcntH[i], hH[i]);
    for (int i = threadIdx.x; i < NB_N; i += 256) if (hN[i]) atomicAdd(&bcntN[i], hN[i]);
}

// ---------------- block-wide exclusive scan helper ----------------
__device__ void scan_block(const int* __restrict__ in, int* __restrict__ out, int n) {
    __shared__ int s[1024];
    int t = threadIdx.x;
    int chunk = (n + 1023) >> 10;
    int b = t * chunk;
    int e = min(b + chunk, n);
    int sum = 0;
    for (int i = b; i < e; ++i) sum += in[i];
    s[t] = sum;
    __syncthreads();
    for (int d = 1; d < 1024; d <<= 1) {
        int v = (t >= d) ? s[t - d] : 0;
        __syncthreads();
        s[t] += v;
        __syncthreads();
    }
    int run = (t > 0) ? s[t - 1] : 0;
    for (int i = b; i < e; ++i) { int v = in[i]; out[i] = run; run += v; }
}
__global__ void k_scan_buckets(const int* __restrict__ bcntE, int* __restrict__ boffE,
                               const int* __restrict__ bcntH, int* __restrict__ boffH,
                               const int* __restrict__ bcntN, int* __restrict__ boffN) {
    if (blockIdx.x == 0)      scan_block(bcntE, boffE, NB_E);
    else if (blockIdx.x == 1) scan_block(bcntH, boffH, NB_H);
    else                      scan_block(bcntN, boffN, NB_N);
}

// ---------------- pass B: chunked scatter, packed int payload (write-combining) ----------------
__device__ void chunk_scatter(const int* __restrict__ keys, const int* __restrict__ vals,
                              int n, int sh, int nb,
                              const int* __restrict__ boff, int* __restrict__ bcur,
                              int* __restrict__ bk, int blk) {
    __shared__ int h[NBMAX], loc[NBMAX], base[NBMAX], hc[NBMAX];
    __shared__ int buf[TILE];
    __shared__ unsigned short bkt[TILE];
    int t0 = blk * TILE;
    int tend = min(t0 + TILE, n);
    int cnt = tend - t0;
    for (int b = threadIdx.x; b < nb; b += 256) { h[b] = 0; hc[b] = 0; }
    __syncthreads();
    for (int i = t0 + threadIdx.x; i < tend; i += 256)
        atomicAdd(&h[keys[i] >> sh], 1);
    __syncthreads();
    if (threadIdx.x == 0) {
        int run = 0;
        for (int b = 0; b < nb; ++b) { loc[b] = run; run += h[b]; }
    }
    __syncthreads();
    for (int b = threadIdx.x; b < nb; b += 256)
        base[b] = boff[b] + atomicAdd(&bcur[b], h[b]);
    __syncthreads();
    for (int i = t0 + threadIdx.x; i < tend; i += 256) {
        int k = keys[i];
        int b = k >> sh;
        int r = loc[b] + atomicAdd(&hc[b], 1);
        buf[r] = ((k - (b << sh)) << 16) | vals[i];   // lk<=127, val<65536
        bkt[r] = (unsigned short)b;
    }
    __syncthreads();
    for (int j = threadIdx.x; j < cnt; j += 256) {
        int b = bkt[j];
        bk[base[b] + (j - loc[b])] = buf[j];          // contiguous block-owned runs
    }
}
__global__ void k_chunk_all(const int* __restrict__ e_row, const int* __restrict__ e_col,
                            const int* __restrict__ n_idx, const int* __restrict__ h_idx,
                            const int* __restrict__ boffE, int* __restrict__ bcurE, int* __restrict__ bkE,
                            const int* __restrict__ boffH, int* __restrict__ bcurH, int* __restrict__ bkH,
                            const int* __restrict__ boffN, int* __restrict__ bcurN, int* __restrict__ bkN) {
    int gb = blockIdx.x;
    if (gb < GB)            chunk_scatter(e_col, e_row, N_EDGES, SH_E, NB_E, boffE, bcurE, bkE, gb);
    else if (gb < 2 * GB)   chunk_scatter(h_idx, n_idx, NNZ_H,  SH_H, NB_H, boffH, bcurH, bkH, gb - GB);
    else                    chunk_scatter(n_idx, h_idx, NNZ_H,  SH_N, NB_N, boffN, bcurN, bkN, gb - 2 * GB);
}

// ---------------- pass C: per-bucket CSR finalize ----------------
__global__ void k_fin_all(const int* __restrict__ bkE, const int* __restrict__ boffE,
                          int* __restrict__ srtE, int* __restrict__ offE,
                          const int* __restrict__ bkH, const int* __restrict__ boffH,
                          int* __restrict__ srtH, int* __restrict__ offH,
                          const int* __restrict__ bkN, const int* __restrict__ boffN,
                          int* __restrict__ srtN, int* __restrict__ offN) {
    __shared__ int koff[KPBMAX];
    __shared__ int kcur[KPBMAX];
    __shared__ int tsum[256];
    int b = blockIdx.x;
    const int* bk; const int* boff; int* srt; int* off;
    int nb, sh, nkeys, total;
    if (b < NB_E) {
        bk = bkE; boff = boffE; srt = srtE; off = offE;
        nb = NB_E; sh = SH_E; nkeys = N_NODES; total = N_EDGES;
    } else if (b < NB_E + NB_H) {
        b -= NB_E;
        bk = bkH; boff = boffH; srt = srtH; off = offH;
        nb = NB_H; sh = SH_H; nkeys = M_HE; total = NNZ_H;
    } else {
        b -= NB_E + NB_H;
        bk = bkN; boff = boffN; srt = srtN; off = offN;
        nb = NB_N; sh = SH_N; nkeys = N_NODES; total = NNZ_H;
    }
    int kpb = 1 << sh;
    int k0 = b << sh;
    int beg = boff[b];
    int end = (b + 1 < nb) ? boff[b + 1] : total;
    int t = threadIdx.x;
    if (t < kpb) { koff[t] = 0; kcur[t] = 0; }
    __syncthreads();
    for (int i = beg + t; i < end; i += 256)
        atomicAdd(&koff[((unsigned)bk[i]) >> 16], 1);
    __syncthreads();
    int v = (t < kpb) ? koff[t] : 0;
    tsum[t] = v;
    __syncthreads();
    for (int d = 1; d < 256; d <<= 1) {
        int u = (t >= d) ? tsum[t - d] : 0;
        __syncthreads();
        tsum[t] += u;
        __syncthreads();
    }
    if (t < kpb) koff[t] = tsum[t] - v;   // exclusive
    __syncthreads();
    if (t < kpb && (k0 + t) < nkeys) off[k0 + t] = beg + koff[t];
    if (b == nb - 1 && t == 0) off[nkeys] = total;
    for (int i = beg + t; i < end; i += 256) {
        int p = bk[i];
        int lk = ((unsigned)p) >> 16;
        int pos = beg + koff[lk] + atomicAdd(&kcur[lk], 1);
        srt[pos] = p & 0xFFFF;
    }
}

// ---------------- register-tiled GEMM: (rows x K) @ (K x 64) -> bf16 ----------------
template<int K, bool SCALE>
__global__ void k_gemm(const float* __restrict__ xin, const float* __restrict__ w,
                       const int* __restrict__ offE, __hip_bfloat16* __restrict__ out) {
    __shared__ float wl[64 * 64];     // [kk][f]
    __shared__ float xs[64 * 68];     // [r][kk], pad 68
    int tid = threadIdx.x;
    int wv = tid >> 6, lane = tid & 63;
    int cg = lane & 15;
    int rg = lane >> 4;
    int rl = wv * 16 + rg * 4;
    int r0 = blockIdx.x * 64;
    float acc[4][4] = {};
    for (int k0 = 0; k0 < K; k0 += 64) {
        {
            const float4* wsrc = (const float4*)(w + k0 * 64);
            float4* wdst = (float4*)wl;
            for (int j = tid; j < 1024; j += 256) wdst[j] = wsrc[j];
        }
        for (int p = tid; p < 1024; p += 256) {
            int r = p >> 4, c4 = p & 15;
            int row = min(r0 + r, N_NODES - 1);
            float4 vv = *(const float4*)(xin + (size_t)row * K + k0 + 4 * c4);
            *(float4*)&xs[r * 68 + 4 * c4] = vv;
        }
        __syncthreads();
#pragma unroll 4
        for (int kk = 0; kk < 64; ++kk) {
            float4 wf = *(const float4*)&wl[kk * 64 + cg * 4];
            float x0 = xs[(rl + 0) * 68 + kk];
            float x1 = xs[(rl + 1) * 68 + kk];
            float x2 = xs[(rl + 2) * 68 + kk];
            float x3 = xs[(rl + 3) * 68 + kk];
            acc[0][0] += x0 * wf.x; acc[0][1] += x0 * wf.y; acc[0][2] += x0 * wf.z; acc[0][3] += x0 * wf.w;
            acc[1][0] += x1 * wf.x; acc[1][1] += x1 * wf.y; acc[1][2] += x1 * wf.z; acc[1][3] += x1 * wf.w;
            acc[2][0] += x2 * wf.x; acc[2][1] += x2 * wf.y; acc[2][2] += x2 * wf.z; acc[2][3] += x2 * wf.w;
            acc[3][0] += x3 * wf.x; acc[3][1] += x3 * wf.y; acc[3][2] += x3 * wf.z; acc[3][3] += x3 * wf.w;
        }
        __syncthreads();
    }
#pragma unroll
    for (int i = 0; i < 4; ++i) {
        int row = r0 + rl + i;
        if (row < N_NODES) {
            float s = 1.0f;
            if (SCALE) {
                float deg = (float)(offE[row + 1] - offE[row]);
                s = rsqrtf(deg + 1.0f);
            }
            __hip_bfloat16 hv[4];
            hv[0] = __float2bfloat16(acc[i][0] * s);
            hv[1] = __float2bfloat16(acc[i][1] * s);
            hv[2] = __float2bfloat16(acc[i][2] * s);
            hv[3] = __float2bfloat16(acc[i][3] * s);
            *(ushort4*)&out[(size_t)row * 64 + cg * 4] = *(ushort4*)hv;
        }
    }
}

// ---------------- GCN gather (bf16 in, fp32 out): out = di*(sum + A'[i]) + b ----------------
template<bool ELU>
__global__ __launch_bounds__(256, 8)
void k_gcn_gather(const int* __restrict__ off, const int* __restrict__ srcs,
                  const __hip_bfloat16* __restrict__ xw, const float* __restrict__ b,
                  float* __restrict__ out) {
    int wid = (blockIdx.x * blockDim.x + threadIdx.x) >> 6;
    int f = threadIdx.x & 63;
    if (wid >= N_NODES) return;
    int beg = off[wid], end = off[wid + 1];
    float a0 = 0, a1 = 0, a2 = 0, a3 = 0, a4 = 0, a5 = 0, a6 = 0, a7 = 0;
    int e = beg;
    for (; e + 8 <= end; e += 8) {
        int s0 = srcs[e], s1 = srcs[e + 1], s2 = srcs[e + 2], s3 = srcs[e + 3];
        int s4 = srcs[e + 4], s5 = srcs[e + 5], s6 = srcs[e + 6], s7 = srcs[e + 7];
        a0 += bf2f(xw[(size_t)s0 * 64 + f]);
        a1 += bf2f(xw[(size_t)s1 * 64 + f]);
        a2 += bf2f(xw[(size_t)s2 * 64 + f]);
        a3 += bf2f(xw[(size_t)s3 * 64 + f]);
        a4 += bf2f(xw[(size_t)s4 * 64 + f]);
        a5 += bf2f(xw[(size_t)s5 * 64 + f]);
        a6 += bf2f(xw[(size_t)s6 * 64 + f]);
        a7 += bf2f(xw[(size_t)s7 * 64 + f]);
    }
    for (; e < end; ++e) a0 += bf2f(xw[(size_t)srcs[e] * 64 + f]);
    float acc = ((a0 + a1) + (a2 + a3)) + ((a4 + a5) + (a6 + a7));
    float di = rsqrtf((float)(end - beg) + 1.0f);
    float v = di * (acc + bf2f(xw[(size_t)wid * 64 + f])) + b[f];
    if (ELU) v = (v > 0.0f) ? v : expm1f(v);
    out[(size_t)wid * 64 + f] = v;
}

// ---------------- hyperedge gather (bf16 in): one BLOCK per hyperedge ----------------
__global__ __launch_bounds__(256, 8)
void k_he_gather(const int* __restrict__ off, const int* __restrict__ nodes,
                 const __hip_bfloat16* __restrict__ xw, float* __restrict__ C) {
    __shared__ float red[4][64];
    int he = blockIdx.x;
    int wv = threadIdx.x >> 6, f = threadIdx.x & 63;
    int beg = off[he], end = off[he + 1];
    int cnt = end - beg;
    int per = (cnt + 3) >> 2;
    int b0 = beg + wv * per;
    int e0 = min(b0 + per, end);
    float a0 = 0, a1 = 0, a2 = 0, a3 = 0;
    int e = b0;
    for (; e + 4 <= e0; e += 4) {
        int s0 = nodes[e], s1 = nodes[e + 1], s2 = nodes[e + 2], s3 = nodes[e + 3];
        a0 += bf2f(xw[(size_t)s0 * 64 + f]);
        a1 += bf2f(xw[(size_t)s1 * 64 + f]);
        a2 += bf2f(xw[(size_t)s2 * 64 + f]);
        a3 += bf2f(xw[(size_t)s3 * 64 + f]);
    }
    for (; e < e0; ++e) a0 += bf2f(xw[(size_t)nodes[e] * 64 + f]);
    red[wv][f] = (a0 + a1) + (a2 + a3);
    __syncthreads();
    if (wv == 0) {
        float tot = (red[0][f] + red[1][f]) + (red[2][f] + red[3][f]);
        float binv = (cnt > 0) ? 1.0f / (float)cnt : 0.0f;
        C[(size_t)he * 64 + f] = binv * tot;
    }
}

// ---------------- node gather (fp32 C in): fused Dinv+bias+ELU (+final gating) ----------------
template<bool ELU, bool FUSE>
__global__ __launch_bounds__(256, 8)
void k_node_gather(const int* __restrict__ off, const int* __restrict__ hes,
                   const float* __restrict__ C, const float* __restrict__ b,
                   float* __restrict__ out,
                   const float* __restrict__ xs, const float* __restrict__ gate,
                   float* __restrict__ z) {
    int wid = (blockIdx.x * blockDim.x + threadIdx.x) >> 6;
    int f = threadIdx.x & 63;
    if (wid >= N_NODES) return;
    int beg = off[wid], end = off[wid + 1];
    float a0 = 0, a1 = 0, a2 = 0, a3 = 0, a4 = 0, a5 = 0, a6 = 0, a7 = 0;
    int e = beg;
    for (; e + 8 <= end; e += 8) {
        int s0 = hes[e], s1 = hes[e + 1], s2 = hes[e + 2], s3 = hes[e + 3];
        int s4 = hes[e + 4], s5 = hes[e + 5], s6 = hes[e + 6], s7 = hes[e + 7];
        a0 += C[(size_t)s0 * 64 + f];
        a1 += C[(size_t)s1 * 64 + f];
        a2 += C[(size_t)s2 * 64 + f];
        a3 += C[(size_t)s3 * 64 + f];
        a4 += C[(size_t)s4 * 64 + f];
        a5 += C[(size_t)s5 * 64 + f];
        a6 += C[(size_t)s6 * 64 + f];
        a7 += C[(size_t)s7 * 64 + f];
    }
    for (; e < end; ++e) a0 += C[(size_t)hes[e] * 64 + f];
    float acc = ((a0 + a1) + (a2 + a3)) + ((a4 + a5) + (a6 + a7));
    float dinv = (end > beg) ? 1.0f / (float)(end - beg) : 0.0f;
    float v = dinv * acc + b[f];
    if (ELU) v = (v > 0.0f) ? v : expm1f(v);
    size_t idx = (size_t)wid * 64 + f;
    out[idx] = v;
    if (FUSE) {
        float a = 1.0f / (1.0f + expf(-gate[0]));
        z[idx] = a * xs[idx] + (1.0f - a) * v;
    }
}

extern "C" void kernel_launch(void* const* d_in, const int* in_sizes, int n_in,
                              void* d_out, int out_size, void* d_ws, size_t ws_size,
                              hipStream_t stream) {
    const float* x      = (const float*)d_in[0];
    const int*   ei     = (const int*)d_in[1];
    const int*   hei    = (const int*)d_in[2];
    const float* gcn1_w = (const float*)d_in[3];
    const float* gcn1_b = (const float*)d_in[4];
    const float* gcn2_w = (const float*)d_in[5];
    const float* gcn2_b = (const float*)d_in[6];
    const float* hyp1_w = (const float*)d_in[7];
    const float* hyp1_b = (const float*)d_in[8];
    const float* hyp2_w = (const float*)d_in[9];
    const float* hyp2_b = (const float*)d_in[10];
    const float* gate   = (const float*)d_in[11];
    float* out = (float*)d_out;

    const int* e_row = ei;               // sources
    const int* e_col = ei + N_EDGES;     // targets
    const int* n_idx = hei;              // node ids
    const int* h_idx = hei + NNZ_H;      // hyperedge ids

    const size_t NV = (size_t)N_NODES * 64;
    float* z_out  = out;
    float* xs_out = out + NV;
    float* xd_out = out + 2 * NV;

    // ---- workspace layout (byte-based) ----
    char* base = (char*)d_ws;
    __hip_bfloat16* Abf = (__hip_bfloat16*)base;            // N*64 bf16 = 6.4 MB
    __hip_bfloat16* Bbf = (__hip_bfloat16*)(base + NV * 2); // 6.4 MB
    float* AGG1 = (float*)(base + NV * 4);                  // 12.8 MB
    float* AGG2 = (float*)(base + NV * 4 + NV * 4);         // 12.8 MB
    float* C    = (float*)(base + NV * 12);                 // M*64 fp32 = 2.56 MB
    int* srtE = (int*)(C + (size_t)M_HE * 64);  // E
    int* srtH = srtE + N_EDGES;          // NNZ
    int* srtN = srtH + NNZ_H;            // NNZ
    int* offE = srtN + NNZ_H;            // N+1
    int* offH = offE + (N_NODES + 1);    // M+1
    int* offN = offH + (M_HE + 1);       // N+1
    // contiguous zero block: bucket counts + cursors
    int* bcntE = offN + (N_NODES + 1);   // NB_E
    int* bcntH = bcntE + NB_E;           // NB_H
    int* bcntN = bcntH + NB_H;           // NB_N
    int* bcurE = bcntN + NB_N;           // NB_E
    int* bcurH = bcurE + NB_E;           // NB_H
    int* bcurN = bcurH + NB_H;           // NB_N
    // scan outputs
    int* boffE = bcurN + NB_N;           // NB_E
    int* boffH = boffE + NB_E;           // NB_H
    int* boffN = boffH + NB_H;           // NB_N
    const size_t zero_ints = 2 * (size_t)(NB_E + NB_H + NB_N);
    // packed sort staging aliases bf16/AGG regions (dead during CSR build)
    int* bkE = (int*)Abf;                // 3.2 MB (fits in 6.4)
    int* bkH = (int*)Bbf;                // 3.2 MB
    int* bkN = (int*)AGG1;               // 3.2 MB

    const int BLK = 256;

    // ---- CSR build ----
    hipMemsetAsync(bcntE, 0, zero_ints * sizeof(int), stream);
    k_hist_all<<<256, BLK, 0, stream>>>(e_col, h_idx, n_idx, bcntE, bcntH, bcntN);
    k_scan_buckets<<<3, 1024, 0, stream>>>(bcntE, boffE, bcntH, boffH, bcntN, boffN);
    k_chunk_all<<<3 * GB, BLK, 0, stream>>>(e_row, e_col, n_idx, h_idx,
                                            boffE, bcurE, bkE,
                                            boffH, bcurH, bkH,
                                            boffN, bcurN, bkN);
    k_fin_all<<<NB_E + NB_H + NB_N, BLK, 0, stream>>>(bkE, boffE, srtE, offE,
                                                      bkH, boffH, srtH, offH,
                                                      bkN, boffN, srtN, offN);

    // ---- GCN layer 1: Abf = dis.*(x@w1) ; AGG1 = ELU(di*(gather+self) + b1) ----
    k_gemm<F_IN, true><<<GG, BLK, 0, stream>>>(x, gcn1_w, offE, Abf);
    k_gcn_gather<true><<<GWN, BLK, 0, stream>>>(offE, srtE, Abf, gcn1_b, AGG1);

    // ---- GCN layer 2 ----
    k_gemm<F_HID, true><<<GG, BLK, 0, stream>>>(AGG1, gcn2_w, offE, Abf);
    k_gcn_gather<false><<<GWN, BLK, 0, stream>>>(offE, srtE, Abf, gcn2_b, xs_out);

    // ---- Hyper layer 1 ----
    k_gemm<F_IN, false><<<GG, BLK, 0, stream>>>(x, hyp1_w, nullptr, Bbf);
    k_he_gather<<<M_HE, BLK, 0, stream>>>(offH, srtH, Bbf, C);
    k_node_gather<true, false><<<GWN, BLK, 0, stream>>>(offN, srtN, C, hyp1_b, AGG2,
                                                        nullptr, nullptr, nullptr);

    // ---- Hyper layer 2 (+ fused gating) ----
    k_gemm<F_HID, false><<<GG, BLK, 0, stream>>>(AGG2, hyp2_w, nullptr, Bbf);
    k_he_gather<<<M_HE, BLK, 0, stream>>>(offH, srtH, Bbf, C);
    k_node_gather<false, true><<<GWN, BLK, 0, stream>>>(offN, srtN, C, hyp2_b, xd_out,
                                                        xs_out, gate, z_out);

    (void)in_sizes; (void)n_in; (void)out_size; (void)ws_size;
}

// Round 12
// 279.788 us; speedup vs baseline: 1.2568x; 1.1530x over previous
//
#include <hip/hip_runtime.h>
#include <hip/hip_bf16.h>

#define N_NODES 50000
#define N_EDGES 800000
#define NNZ_H   800000
#define M_HE    10000
#define F_IN    128
#define F_HID   64

// coarse-bucket geometry for the two-level counting sort
#define SH_E 7
#define NB_E ((N_NODES + 127) >> 7)     // 391
#define SH_H 5
#define NB_H ((M_HE + 31) >> 5)         // 313
#define SH_N 7
#define NB_N ((N_NODES + 127) >> 7)     // 391
#define TILE 4096
#define GB   ((N_EDGES + TILE - 1) / TILE)   // 196 (E == NNZ)
#define NBMAX 400
#define KPBMAX 128
#define GG  782     // (N_NODES+63)/64 GEMM blocks
#define GWN 12500   // N_NODES/4 wave-per-node blocks

static __device__ __forceinline__ float bflo(unsigned v) { return __uint_as_float(v << 16); }
static __device__ __forceinline__ float bfhi(unsigned v) { return __uint_as_float(v & 0xFFFF0000u); }

// ---------------- pass A: fused bucket histograms ----------------
__global__ void k_hist_all(const int* __restrict__ e_col, const int* __restrict__ h_idx,
                           const int* __restrict__ n_idx,
                           int* __restrict__ bcntE, int* __restrict__ bcntH, int* __restrict__ bcntN) {
    __shared__ int hE[NB_E], hH[NB_H], hN[NB_N];
    for (int i = threadIdx.x; i < NB_E; i += 256) hE[i] = 0;
    for (int i = threadIdx.x; i < NB_H; i += 256) hH[i] = 0;
    for (int i = threadIdx.x; i < NB_N; i += 256) hN[i] = 0;
    __syncthreads();
    int stride = gridDim.x * 256;
    for (int i = blockIdx.x * 256 + threadIdx.x; i < N_EDGES; i += stride) {
        atomicAdd(&hE[e_col[i] >> SH_E], 1);
        atomicAdd(&hH[h_idx[i] >> SH_H], 1);
        atomicAdd(&hN[n_idx[i] >> SH_N], 1);
    }
    __syncthreads();
    for (int i = threadIdx.x; i < NB_E; i += 256) if (hE[i]) atomicAdd(&bcntE[i], hE[i]);
    for (int i = threadIdx.x; i < NB_H; i += 256) if (hH[i]) atomicAdd(&bcntH[i], hH[i]);
    for (int i = threadIdx.x; i < NB_N; i += 256) if (hN[i]) atomicAdd(&bcntN[i], hN[i]);
}

// ---------------- block-wide exclusive scan helper ----------------
__device__ void scan_block(const int* __restrict__ in, int* __restrict__ out, int n) {
    __shared__ int s[1024];
    int t = threadIdx.x;
    int chunk = (n + 1023) >> 10;
    int b = t * chunk;
    int e = min(b + chunk, n);
    int sum = 0;
    for (int i = b; i < e; ++i) sum += in[i];
    s[t] = sum;
    __syncthreads();
    for (int d = 1; d < 1024; d <<= 1) {
        int v = (t >= d) ? s[t - d] : 0;
        __syncthreads();
        s[t] += v;
        __syncthreads();
    }
    int run = (t > 0) ? s[t - 1] : 0;
    for (int i = b; i < e; ++i) { int v = in[i]; out[i] = run; run += v; }
}
__global__ void k_scan_buckets(const int* __restrict__ bcntE, int* __restrict__ boffE,
                               const int* __restrict__ bcntH, int* __restrict__ boffH,
                               const int* __restrict__ bcntN, int* __restrict__ boffN) {
    if (blockIdx.x == 0)      scan_block(bcntE, boffE, NB_E);
    else if (blockIdx.x == 1) scan_block(bcntH, boffH, NB_H);
    else                      scan_block(bcntN, boffN, NB_N);
}

// ---------------- pass B: chunked scatter, packed payload (write-combining) ----------------
__device__ void chunk_scatter(const int* __restrict__ keys, const int* __restrict__ vals,
                              int n, int sh, int nb,
                              const int* __restrict__ boff, int* __restrict__ bcur,
                              int* __restrict__ bk, int blk) {
    __shared__ int h[NBMAX], loc[NBMAX], base[NBMAX], hc[NBMAX];
    __shared__ int buf[TILE];
    __shared__ unsigned short bkt[TILE];
    int t0 = blk * TILE;
    int tend = min(t0 + TILE, n);
    int cnt = tend - t0;
    for (int b = threadIdx.x; b < nb; b += 256) { h[b] = 0; hc[b] = 0; }
    __syncthreads();
    for (int i = t0 + threadIdx.x; i < tend; i += 256)
        atomicAdd(&h[keys[i] >> sh], 1);
    __syncthreads();
    if (threadIdx.x == 0) {
        int run = 0;
        for (int b = 0; b < nb; ++b) { loc[b] = run; run += h[b]; }
    }
    __syncthreads();
    for (int b = threadIdx.x; b < nb; b += 256)
        base[b] = boff[b] + atomicAdd(&bcur[b], h[b]);
    __syncthreads();
    for (int i = t0 + threadIdx.x; i < tend; i += 256) {
        int k = keys[i];
        int b = k >> sh;
        int r = loc[b] + atomicAdd(&hc[b], 1);
        buf[r] = ((k - (b << sh)) << 16) | vals[i];
        bkt[r] = (unsigned short)b;
    }
    __syncthreads();
    for (int j = threadIdx.x; j < cnt; j += 256) {
        int b = bkt[j];
        bk[base[b] + (j - loc[b])] = buf[j];
    }
}
__global__ void k_chunk_all(const int* __restrict__ e_row, const int* __restrict__ e_col,
                            const int* __restrict__ n_idx, const int* __restrict__ h_idx,
                            const int* __restrict__ boffE, int* __restrict__ bcurE, int* __restrict__ bkE,
                            const int* __restrict__ boffH, int* __restrict__ bcurH, int* __restrict__ bkH,
                            const int* __restrict__ boffN, int* __restrict__ bcurN, int* __restrict__ bkN) {
    int gb = blockIdx.x;
    if (gb < GB)            chunk_scatter(e_col, e_row, N_EDGES, SH_E, NB_E, boffE, bcurE, bkE, gb);
    else if (gb < 2 * GB)   chunk_scatter(h_idx, n_idx, NNZ_H,  SH_H, NB_H, boffH, bcurH, bkH, gb - GB);
    else                    chunk_scatter(n_idx, h_idx, NNZ_H,  SH_N, NB_N, boffN, bcurN, bkN, gb - 2 * GB);
}

// ---------------- pass C: per-bucket CSR finalize ----------------
__global__ void k_fin_all(const int* __restrict__ bkE, const int* __restrict__ boffE,
                          int* __restrict__ srtE, int* __restrict__ offE,
                          const int* __restrict__ bkH, const int* __restrict__ boffH,
                          int* __restrict__ srtH, int* __restrict__ offH,
                          const int* __restrict__ bkN, const int* __restrict__ boffN,
                          int* __restrict__ srtN, int* __restrict__ offN) {
    __shared__ int koff[KPBMAX];
    __shared__ int kcur[KPBMAX];
    __shared__ int tsum[256];
    int b = blockIdx.x;
    const int* bk; const int* boff; int* srt; int* off;
    int nb, sh, nkeys, total;
    if (b < NB_E) {
        bk = bkE; boff = boffE; srt = srtE; off = offE;
        nb = NB_E; sh = SH_E; nkeys = N_NODES; total = N_EDGES;
    } else if (b < NB_E + NB_H) {
        b -= NB_E;
        bk = bkH; boff = boffH; srt = srtH; off = offH;
        nb = NB_H; sh = SH_H; nkeys = M_HE; total = NNZ_H;
    } else {
        b -= NB_E + NB_H;
        bk = bkN; boff = boffN; srt = srtN; off = offN;
        nb = NB_N; sh = SH_N; nkeys = N_NODES; total = NNZ_H;
    }
    int kpb = 1 << sh;
    int k0 = b << sh;
    int beg = boff[b];
    int end = (b + 1 < nb) ? boff[b + 1] : total;
    int t = threadIdx.x;
    if (t < kpb) { koff[t] = 0; kcur[t] = 0; }
    __syncthreads();
    for (int i = beg + t; i < end; i += 256)
        atomicAdd(&koff[((unsigned)bk[i]) >> 16], 1);
    __syncthreads();
    int v = (t < kpb) ? koff[t] : 0;
    tsum[t] = v;
    __syncthreads();
    for (int d = 1; d < 256; d <<= 1) {
        int u = (t >= d) ? tsum[t - d] : 0;
        __syncthreads();
        tsum[t] += u;
        __syncthreads();
    }
    if (t < kpb) koff[t] = tsum[t] - v;
    __syncthreads();
    if (t < kpb && (k0 + t) < nkeys) off[k0 + t] = beg + koff[t];
    if (b == nb - 1 && t == 0) off[nkeys] = total;
    for (int i = beg + t; i < end; i += 256) {
        int p = bk[i];
        int lk = ((unsigned)p) >> 16;
        int pos = beg + koff[lk] + atomicAdd(&kcur[lk], 1);
        srt[pos] = p & 0xFFFF;
    }
}

// ---------------- register-tiled GEMM body -> bf16 out ----------------
template<int K, bool SCALE>
__device__ __forceinline__ void gemm_body(const float* __restrict__ xin, const float* __restrict__ w,
                                          const int* __restrict__ offE, __hip_bfloat16* __restrict__ out,
                                          int blk, float* __restrict__ wl, float* __restrict__ xs) {
    int tid = threadIdx.x;
    int wv = tid >> 6, lane = tid & 63;
    int cg = lane & 15;
    int rg = lane >> 4;
    int rl = wv * 16 + rg * 4;
    int r0 = blk * 64;
    float acc[4][4] = {};
    for (int k0 = 0; k0 < K; k0 += 64) {
        {
            const float4* wsrc = (const float4*)(w + k0 * 64);
            float4* wdst = (float4*)wl;
            for (int j = tid; j < 1024; j += 256) wdst[j] = wsrc[j];
        }
        for (int p = tid; p < 1024; p += 256) {
            int r = p >> 4, c4 = p & 15;
            int row = min(r0 + r, N_NODES - 1);
            float4 vv = *(const float4*)(xin + (size_t)row * K + k0 + 4 * c4);
            *(float4*)&xs[r * 68 + 4 * c4] = vv;
        }
        __syncthreads();
#pragma unroll 4
        for (int kk = 0; kk < 64; ++kk) {
            float4 wf = *(const float4*)&wl[kk * 64 + cg * 4];
            float x0 = xs[(rl + 0) * 68 + kk];
            float x1 = xs[(rl + 1) * 68 + kk];
            float x2 = xs[(rl + 2) * 68 + kk];
            float x3 = xs[(rl + 3) * 68 + kk];
            acc[0][0] += x0 * wf.x; acc[0][1] += x0 * wf.y; acc[0][2] += x0 * wf.z; acc[0][3] += x0 * wf.w;
            acc[1][0] += x1 * wf.x; acc[1][1] += x1 * wf.y; acc[1][2] += x1 * wf.z; acc[1][3] += x1 * wf.w;
            acc[2][0] += x2 * wf.x; acc[2][1] += x2 * wf.y; acc[2][2] += x2 * wf.z; acc[2][3] += x2 * wf.w;
            acc[3][0] += x3 * wf.x; acc[3][1] += x3 * wf.y; acc[3][2] += x3 * wf.z; acc[3][3] += x3 * wf.w;
        }
        __syncthreads();
    }
#pragma unroll
    for (int i = 0; i < 4; ++i) {
        int row = r0 + rl + i;
        if (row < N_NODES) {
            float s = 1.0f;
            if (SCALE) {
                float deg = (float)(offE[row + 1] - offE[row]);
                s = rsqrtf(deg + 1.0f);
            }
            __hip_bfloat16 hv[4];
            hv[0] = __float2bfloat16(acc[i][0] * s);
            hv[1] = __float2bfloat16(acc[i][1] * s);
            hv[2] = __float2bfloat16(acc[i][2] * s);
            hv[3] = __float2bfloat16(acc[i][3] * s);
            *(ushort4*)&out[(size_t)row * 64 + cg * 4] = *(ushort4*)hv;
        }
    }
}

// dual GEMM: blocks [0,GG) -> op1 (SCALE), [GG,2GG) -> op2 (no scale)
template<int K>
__global__ void k_gemm_dual(const float* __restrict__ in1, const float* __restrict__ w1,
                            const int* __restrict__ offE, __hip_bfloat16* __restrict__ out1,
                            const float* __restrict__ in2, const float* __restrict__ w2,
                            __hip_bfloat16* __restrict__ out2) {
    __shared__ float wl[64 * 64];
    __shared__ float xs[64 * 68];
    if (blockIdx.x < GG) gemm_body<K, true>(in1, w1, offE, out1, blockIdx.x, wl, xs);
    else                 gemm_body<K, false>(in2, w2, nullptr, out2, blockIdx.x - GG, wl, xs);
}

// ---------------- 2-wide GCN gather body (bf16 in, fp32 out) ----------------
template<bool ELU>
__device__ __forceinline__ void gcn_gather_body(const int* __restrict__ off, const int* __restrict__ srcs,
                                                const __hip_bfloat16* __restrict__ xw,
                                                const float* __restrict__ b,
                                                float* __restrict__ out, int blk) {
    int tid = threadIdx.x;
    int wv = tid >> 6, lane = tid & 63;
    int h = lane >> 5, l = lane & 31;
    int wid = blk * 4 + wv;
    if (wid >= N_NODES) return;
    int beg = off[wid];
    int cnt = off[wid + 1] - beg;
    const unsigned* xwu = (const unsigned*)xw;
    float ax0 = 0, ay0 = 0, ax1 = 0, ay1 = 0, ax2 = 0, ay2 = 0, ax3 = 0, ay3 = 0;
    int k = h;
    for (; k + 6 < cnt; k += 8) {
        int s0 = srcs[beg + k];
        int s1 = srcs[beg + k + 2];
        int s2 = srcs[beg + k + 4];
        int s3 = srcs[beg + k + 6];
        unsigned v0 = xwu[(size_t)s0 * 32 + l];
        unsigned v1 = xwu[(size_t)s1 * 32 + l];
        unsigned v2 = xwu[(size_t)s2 * 32 + l];
        unsigned v3 = xwu[(size_t)s3 * 32 + l];
        ax0 += bflo(v0); ay0 += bfhi(v0);
        ax1 += bflo(v1); ay1 += bfhi(v1);
        ax2 += bflo(v2); ay2 += bfhi(v2);
        ax3 += bflo(v3); ay3 += bfhi(v3);
    }
    for (; k < cnt; k += 2) {
        unsigned v = xwu[(size_t)srcs[beg + k] * 32 + l];
        ax0 += bflo(v); ay0 += bfhi(v);
    }
    float tx = (ax0 + ax1) + (ax2 + ax3);
    float ty = (ay0 + ay1) + (ay2 + ay3);
    tx += __shfl_xor(tx, 32);
    ty += __shfl_xor(ty, 32);
    unsigned sv = xwu[(size_t)wid * 32 + l];
    float di = rsqrtf((float)cnt + 1.0f);
    float vx = di * (tx + bflo(sv)) + b[2 * l];
    float vy = di * (ty + bfhi(sv)) + b[2 * l + 1];
    if (ELU) {
        vx = (vx > 0.0f) ? vx : expm1f(vx);
        vy = (vy > 0.0f) ? vy : expm1f(vy);
    }
    if (h == 0) *(float2*)(out + (size_t)wid * 64 + 2 * l) = make_float2(vx, vy);
}

// ---------------- 2-wide hyperedge gather body (bf16 in, fp32 C out) ----------------
__device__ __forceinline__ void he_gather_body(const int* __restrict__ off, const int* __restrict__ nodes,
                                               const __hip_bfloat16* __restrict__ xw,
                                               float* __restrict__ C, int he, float2 (*red)[32]) {
    int tid = threadIdx.x;
    int wv = tid >> 6, lane = tid & 63;
    int h = lane >> 5, l = lane & 31;
    int beg = off[he], end = off[he + 1];
    int cnt = end - beg;
    int per = (cnt + 3) >> 2;
    int b0 = beg + wv * per;
    int e0 = min(b0 + per, end);
    int c2 = e0 - b0;
    const unsigned* xwu = (const unsigned*)xw;
    float ax0 = 0, ay0 = 0, ax1 = 0, ay1 = 0;
    int k = h;
    for (; k + 2 < c2; k += 4) {
        unsigned v0 = xwu[(size_t)nodes[b0 + k] * 32 + l];
        unsigned v1 = xwu[(size_t)nodes[b0 + k + 2] * 32 + l];
        ax0 += bflo(v0); ay0 += bfhi(v0);
        ax1 += bflo(v1); ay1 += bfhi(v1);
    }
    for (; k < c2; k += 2) {
        unsigned v = xwu[(size_t)nodes[b0 + k] * 32 + l];
        ax0 += bflo(v); ay0 += bfhi(v);
    }
    float tx = ax0 + ax1;
    float ty = ay0 + ay1;
    tx += __shfl_xor(tx, 32);
    ty += __shfl_xor(ty, 32);
    if (h == 0) red[wv][l] = make_float2(tx, ty);
    __syncthreads();
    if (tid < 32) {
        float2 r0 = red[0][tid], r1 = red[1][tid], r2 = red[2][tid], r3 = red[3][tid];
        float binv = (cnt > 0) ? 1.0f / (float)cnt : 0.0f;
        float2 o = make_float2((r0.x + r1.x + r2.x + r3.x) * binv,
                               (r0.y + r1.y + r2.y + r3.y) * binv);
        *(float2*)(C + (size_t)he * 64 + 2 * tid) = o;
    }
}

// dual gather: blocks [0,GWN) -> gcn gather, [GWN,GWN+M_HE) -> hyperedge gather
template<bool ELU>
__global__ __launch_bounds__(256, 8)
void k_gather_dual(const int* __restrict__ offE, const int* __restrict__ srtE,
                   const __hip_bfloat16* __restrict__ A, const float* __restrict__ gb,
                   float* __restrict__ aggOut,
                   const int* __restrict__ offH, const int* __restrict__ srtH,
                   const __hip_bfloat16* __restrict__ B, float* __restrict__ C) {
    __shared__ float2 red[4][32];
    if (blockIdx.x < GWN) gcn_gather_body<ELU>(offE, srtE, A, gb, aggOut, blockIdx.x);
    else                  he_gather_body(offH, srtH, B, C, blockIdx.x - GWN, red);
}

// ---------------- 2-wide node gather (fp32 C in): Dinv+bias+ELU (+gating) ----------------
template<bool ELU, bool FUSE>
__global__ __launch_bounds__(256, 8)
void k_node_gather(const int* __restrict__ off, const int* __restrict__ hes,
                   const float* __restrict__ C, const float* __restrict__ b,
                   float* __restrict__ out,
                   const float* __restrict__ xs, const float* __restrict__ gate,
                   float* __restrict__ z) {
    int tid = threadIdx.x;
    int wv = tid >> 6, lane = tid & 63;
    int h = lane >> 5, l = lane & 31;
    int wid = blockIdx.x * 4 + wv;
    if (wid >= N_NODES) return;
    int beg = off[wid];
    int cnt = off[wid + 1] - beg;
    float ax0 = 0, ay0 = 0, ax1 = 0, ay1 = 0, ax2 = 0, ay2 = 0, ax3 = 0, ay3 = 0;
    int k = h;
    for (; k + 6 < cnt; k += 8) {
        float2 c0 = *(const float2*)(C + (size_t)hes[beg + k] * 64 + 2 * l);
        float2 c1 = *(const float2*)(C + (size_t)hes[beg + k + 2] * 64 + 2 * l);
        float2 c2 = *(const float2*)(C + (size_t)hes[beg + k + 4] * 64 + 2 * l);
        float2 c3 = *(const float2*)(C + (size_t)hes[beg + k + 6] * 64 + 2 * l);
        ax0 += c0.x; ay0 += c0.y;
        ax1 += c1.x; ay1 += c1.y;
        ax2 += c2.x; ay2 += c2.y;
        ax3 += c3.x; ay3 += c3.y;
    }
    for (; k < cnt; k += 2) {
        float2 c = *(const float2*)(C + (size_t)hes[beg + k] * 64 + 2 * l);
        ax0 += c.x; ay0 += c.y;
    }
    float tx = (ax0 + ax1) + (ax2 + ax3);
    float ty = (ay0 + ay1) + (ay2 + ay3);
    tx += __shfl_xor(tx, 32);
    ty += __shfl_xor(ty, 32);
    float dinv = (cnt > 0) ? 1.0f / (float)cnt : 0.0f;
    float vx = dinv * tx + b[2 * l];
    float vy = dinv * ty + b[2 * l + 1];
    if (ELU) {
        vx = (vx > 0.0f) ? vx : expm1f(vx);
        vy = (vy > 0.0f) ? vy : expm1f(vy);
    }
    if (h == 0) {
        size_t idx = (size_t)wid * 64 + 2 * l;
        *(float2*)(out + idx) = make_float2(vx, vy);
        if (FUSE) {
            float a = 1.0f / (1.0f + expf(-gate[0]));
            float2 s = *(const float2*)(xs + idx);
            *(float2*)(z + idx) = make_float2(a * s.x + (1.0f - a) * vx,
                                              a * s.y + (1.0f - a) * vy);
        }
    }
}

extern "C" void kernel_launch(void* const* d_in, const int* in_sizes, int n_in,
                              void* d_out, int out_size, void* d_ws, size_t ws_size,
                              hipStream_t stream) {
    const float* x      = (const float*)d_in[0];
    const int*   ei     = (const int*)d_in[1];
    const int*   hei    = (const int*)d_in[2];
    const float* gcn1_w = (const float*)d_in[3];
    const float* gcn1_b = (const float*)d_in[4];
    const float* gcn2_w = (const float*)d_in[5];
    const float* gcn2_b = (const float*)d_in[6];
    const float* hyp1_w = (const float*)d_in[7];
    const float* hyp1_b = (const float*)d_in[8];
    const float* hyp2_w = (const float*)d_in[9];
    const float* hyp2_b = (const float*)d_in[10];
    const float* gate   = (const float*)d_in[11];
    float* out = (float*)d_out;

    const int* e_row = ei;
    const int* e_col = ei + N_EDGES;
    const int* n_idx = hei;
    const int* h_idx = hei + NNZ_H;

    const size_t NV = (size_t)N_NODES * 64;
    float* z_out  = out;
    float* xs_out = out + NV;
    float* xd_out = out + 2 * NV;

    // ---- workspace layout ----
    char* base = (char*)d_ws;
    __hip_bfloat16* Abf = (__hip_bfloat16*)base;            // 6.4 MB
    __hip_bfloat16* Bbf = (__hip_bfloat16*)(base + NV * 2); // 6.4 MB
    float* AGG1 = (float*)(base + NV * 4);                  // 12.8 MB
    float* AGG2 = (float*)(base + NV * 8);                  // 12.8 MB
    float* C    = (float*)(base + NV * 12);                 // 2.56 MB
    int* srtE = (int*)(C + (size_t)M_HE * 64);
    int* srtH = srtE + N_EDGES;
    int* srtN = srtH + NNZ_H;
    int* offE = srtN + NNZ_H;
    int* offH = offE + (N_NODES + 1);
    int* offN = offH + (M_HE + 1);
    int* bcntE = offN + (N_NODES + 1);
    int* bcntH = bcntE + NB_E;
    int* bcntN = bcntH + NB_H;
    int* bcurE = bcntN + NB_N;
    int* bcurH = bcurE + NB_E;
    int* bcurN = bcurH + NB_H;
    int* boffE = bcurN + NB_N;
    int* boffH = boffE + NB_E;
    int* boffN = boffH + NB_H;
    const size_t zero_ints = 2 * (size_t)(NB_E + NB_H + NB_N);
    int* bkE = (int*)Abf;
    int* bkH = (int*)Bbf;
    int* bkN = (int*)AGG1;

    const int BLK = 256;

    // ---- CSR build ----
    hipMemsetAsync(bcntE, 0, zero_ints * sizeof(int), stream);
    k_hist_all<<<256, BLK, 0, stream>>>(e_col, h_idx, n_idx, bcntE, bcntH, bcntN);
    k_scan_buckets<<<3, 1024, 0, stream>>>(bcntE, boffE, bcntH, boffH, bcntN, boffN);
    k_chunk_all<<<3 * GB, BLK, 0, stream>>>(e_row, e_col, n_idx, h_idx,
                                            boffE, bcurE, bkE,
                                            boffH, bcurH, bkH,
                                            boffN, bcurN, bkN);
    k_fin_all<<<NB_E + NB_H + NB_N, BLK, 0, stream>>>(bkE, boffE, srtE, offE,
                                                      bkH, boffH, srtH, offH,
                                                      bkN, boffN, srtN, offN);

    // ---- G13: Abf = dis.*(x@w1)  ||  Bbf = x@hw1 ----
    k_gemm_dual<F_IN><<<2 * GG, BLK, 0, stream>>>(x, gcn1_w, offE, Abf, x, hyp1_w, Bbf);
    // ---- DG1: AGG1 = ELU(gcnGather(Abf))  ||  C = heGather(Bbf) ----
    k_gather_dual<true><<<GWN + M_HE, BLK, 0, stream>>>(offE, srtE, Abf, gcn1_b, AGG1,
                                                        offH, srtH, Bbf, C);
    // ---- nodeG1: AGG2 = ELU(Dinv*(H C) + hb1) ----
    k_node_gather<true, false><<<GWN, BLK, 0, stream>>>(offN, srtN, C, hyp1_b, AGG2,
                                                        nullptr, nullptr, nullptr);
    // ---- G24: Abf = dis.*(AGG1@w2)  ||  Bbf = AGG2@hw2 ----
    k_gemm_dual<F_HID><<<2 * GG, BLK, 0, stream>>>(AGG1, gcn2_w, offE, Abf, AGG2, hyp2_w, Bbf);
    // ---- DG2: xs_out = gcnGather(Abf)  ||  C = heGather(Bbf) ----
    k_gather_dual<false><<<GWN + M_HE, BLK, 0, stream>>>(offE, srtE, Abf, gcn2_b, xs_out,
                                                         offH, srtH, Bbf, C);
    // ---- nodeG2 + gating ----
    k_node_gather<false, true><<<GWN, BLK, 0, stream>>>(offN, srtN, C, hyp2_b, xd_out,
                                                        xs_out, gate, z_out);

    (void)in_sizes; (void)n_in; (void)out_size; (void)ws_size;
}

// Round 13
// 259.878 us; speedup vs baseline: 1.3531x; 1.0766x over previous
//
#include <hip/hip_runtime.h>
#include <hip/hip_bf16.h>

#define N_NODES 50000
#define N_EDGES 800000
#define NNZ_H   800000
#define M_HE    10000
#define F_IN    128
#define F_HID   64

// coarse-bucket geometry for the two-level counting sort
#define SH_E 7
#define NB_E ((N_NODES + 127) >> 7)     // 391
#define SH_H 5
#define NB_H ((M_HE + 31) >> 5)         // 313
#define SH_N 7
#define NB_N ((N_NODES + 127) >> 7)     // 391
#define TILE 4096
#define GB   ((N_EDGES + TILE - 1) / TILE)   // 196 (E == NNZ)
#define NBMAX 400
#define KPBMAX 128
#define GG  782     // (N_NODES+63)/64 GEMM blocks
#define GWN 12500   // N_NODES/4 wave-per-node blocks

static __device__ __forceinline__ float bflo(unsigned v) { return __uint_as_float(v << 16); }
static __device__ __forceinline__ float bfhi(unsigned v) { return __uint_as_float(v & 0xFFFF0000u); }

// ---------------- pass A: fused bucket histograms (int2 reads) ----------------
__global__ void k_hist_all(const int* __restrict__ e_col, const int* __restrict__ h_idx,
                           const int* __restrict__ n_idx,
                           int* __restrict__ bcntE, int* __restrict__ bcntH, int* __restrict__ bcntN) {
    __shared__ int hE[NB_E], hH[NB_H], hN[NB_N];
    for (int i = threadIdx.x; i < NB_E; i += 256) hE[i] = 0;
    for (int i = threadIdx.x; i < NB_H; i += 256) hH[i] = 0;
    for (int i = threadIdx.x; i < NB_N; i += 256) hN[i] = 0;
    __syncthreads();
    const int2* ec2 = (const int2*)e_col;
    const int2* hi2 = (const int2*)h_idx;
    const int2* ni2 = (const int2*)n_idx;
    int stride = gridDim.x * 256;
    for (int i = blockIdx.x * 256 + threadIdx.x; i < N_EDGES / 2; i += stride) {
        int2 e = ec2[i];
        atomicAdd(&hE[e.x >> SH_E], 1);
        atomicAdd(&hE[e.y >> SH_E], 1);
        int2 hh = hi2[i];
        atomicAdd(&hH[hh.x >> SH_H], 1);
        atomicAdd(&hH[hh.y >> SH_H], 1);
        int2 nn = ni2[i];
        atomicAdd(&hN[nn.x >> SH_N], 1);
        atomicAdd(&hN[nn.y >> SH_N], 1);
    }
    __syncthreads();
    for (int i = threadIdx.x; i < NB_E; i += 256) if (hE[i]) atomicAdd(&bcntE[i], hE[i]);
    for (int i = threadIdx.x; i < NB_H; i += 256) if (hH[i]) atomicAdd(&bcntH[i], hH[i]);
    for (int i = threadIdx.x; i < NB_N; i += 256) if (hN[i]) atomicAdd(&bcntN[i], hN[i]);
}

// ---------------- in-LDS exclusive scan of bcnt[0..nb) (nb <= 512), 256 threads ----------------
__device__ void scan_to_lds(const int* __restrict__ in, int* __restrict__ soff, int nb,
                            int* __restrict__ tsum) {
    int t = threadIdx.x;
    int v0 = (2 * t < nb) ? in[2 * t] : 0;
    int v1 = (2 * t + 1 < nb) ? in[2 * t + 1] : 0;
    tsum[t] = v0 + v1;
    __syncthreads();
    for (int d = 1; d < 256; d <<= 1) {
        int u = (t >= d) ? tsum[t - d] : 0;
        __syncthreads();
        tsum[t] += u;
        __syncthreads();
    }
    int run = (t > 0) ? tsum[t - 1] : 0;
    if (2 * t < nb) soff[2 * t] = run;
    if (2 * t + 1 < nb) soff[2 * t + 1] = run + v0;
    __syncthreads();
}

// ---------------- pass B: chunked scatter, packed payload, self-scanned offsets ----------------
__device__ void chunk_scatter(const int* __restrict__ keys, const int* __restrict__ vals,
                              int n, int sh, int nb,
                              const int* __restrict__ bcnt, int* __restrict__ bcur,
                              int* __restrict__ bk, int blk) {
    __shared__ int h[NBMAX], loc[NBMAX], base[NBMAX], hc[NBMAX], soff[NBMAX];
    __shared__ int tsum[256];
    __shared__ int buf[TILE];
    __shared__ unsigned short bkt[TILE];
    scan_to_lds(bcnt, soff, nb, tsum);
    int t0 = blk * TILE;
    int tend = min(t0 + TILE, n);
    int cnt = tend - t0;
    for (int b = threadIdx.x; b < nb; b += 256) { h[b] = 0; hc[b] = 0; }
    __syncthreads();
    for (int i = t0 + threadIdx.x; i < tend; i += 256)
        atomicAdd(&h[keys[i] >> sh], 1);
    __syncthreads();
    if (threadIdx.x == 0) {
        int run = 0;
        for (int b = 0; b < nb; ++b) { loc[b] = run; run += h[b]; }
    }
    __syncthreads();
    for (int b = threadIdx.x; b < nb; b += 256)
        base[b] = soff[b] + atomicAdd(&bcur[b], h[b]);
    __syncthreads();
    for (int i = t0 + threadIdx.x; i < tend; i += 256) {
        int k = keys[i];
        int b = k >> sh;
        int r = loc[b] + atomicAdd(&hc[b], 1);
        buf[r] = ((k - (b << sh)) << 16) | vals[i];
        bkt[r] = (unsigned short)b;
    }
    __syncthreads();
    for (int j = threadIdx.x; j < cnt; j += 256) {
        int b = bkt[j];
        bk[base[b] + (j - loc[b])] = buf[j];
    }
}
__global__ void k_chunk_all(const int* __restrict__ e_row, const int* __restrict__ e_col,
                            const int* __restrict__ n_idx, const int* __restrict__ h_idx,
                            const int* __restrict__ bcntE, int* __restrict__ bcurE, int* __restrict__ bkE,
                            const int* __restrict__ bcntH, int* __restrict__ bcurH, int* __restrict__ bkH,
                            const int* __restrict__ bcntN, int* __restrict__ bcurN, int* __restrict__ bkN) {
    int gb = blockIdx.x;
    if (gb < GB)            chunk_scatter(e_col, e_row, N_EDGES, SH_E, NB_E, bcntE, bcurE, bkE, gb);
    else if (gb < 2 * GB)   chunk_scatter(h_idx, n_idx, NNZ_H,  SH_H, NB_H, bcntH, bcurH, bkH, gb - GB);
    else                    chunk_scatter(n_idx, h_idx, NNZ_H,  SH_N, NB_N, bcntN, bcurN, bkN, gb - 2 * GB);
}

// ---------------- pass C: per-bucket CSR finalize, self-scanned offsets ----------------
__global__ void k_fin_all(const int* __restrict__ bkE, const int* __restrict__ bcntE,
                          int* __restrict__ srtE, int* __restrict__ offE,
                          const int* __restrict__ bkH, const int* __restrict__ bcntH,
                          int* __restrict__ srtH, int* __restrict__ offH,
                          const int* __restrict__ bkN, const int* __restrict__ bcntN,
                          int* __restrict__ srtN, int* __restrict__ offN) {
    __shared__ int koff[KPBMAX];
    __shared__ int kcur[KPBMAX];
    __shared__ int tsum[256];
    __shared__ int soff[NBMAX];
    int b = blockIdx.x;
    const int* bk; const int* bcnt; int* srt; int* off;
    int nb, sh, nkeys, total;
    if (b < NB_E) {
        bk = bkE; bcnt = bcntE; srt = srtE; off = offE;
        nb = NB_E; sh = SH_E; nkeys = N_NODES; total = N_EDGES;
    } else if (b < NB_E + NB_H) {
        b -= NB_E;
        bk = bkH; bcnt = bcntH; srt = srtH; off = offH;
        nb = NB_H; sh = SH_H; nkeys = M_HE; total = NNZ_H;
    } else {
        b -= NB_E + NB_H;
        bk = bkN; bcnt = bcntN; srt = srtN; off = offN;
        nb = NB_N; sh = SH_N; nkeys = N_NODES; total = NNZ_H;
    }
    scan_to_lds(bcnt, soff, nb, tsum);
    int kpb = 1 << sh;
    int k0 = b << sh;
    int beg = soff[b];
    int end = (b + 1 < nb) ? soff[b + 1] : total;
    int t = threadIdx.x;
    if (t < kpb) { koff[t] = 0; kcur[t] = 0; }
    __syncthreads();
    for (int i = beg + t; i < end; i += 256)
        atomicAdd(&koff[((unsigned)bk[i]) >> 16], 1);
    __syncthreads();
    int v = (t < kpb) ? koff[t] : 0;
    tsum[t] = v;
    __syncthreads();
    for (int d = 1; d < 256; d <<= 1) {
        int u = (t >= d) ? tsum[t - d] : 0;
        __syncthreads();
        tsum[t] += u;
        __syncthreads();
    }
    if (t < kpb) koff[t] = tsum[t] - v;
    __syncthreads();
    if (t < kpb && (k0 + t) < nkeys) off[k0 + t] = beg + koff[t];
    if (b == nb - 1 && t == 0) off[nkeys] = total;
    for (int i = beg + t; i < end; i += 256) {
        int p = bk[i];
        int lk = ((unsigned)p) >> 16;
        int pos = beg + koff[lk] + atomicAdd(&kcur[lk], 1);
        srt[pos] = p & 0xFFFF;
    }
}

// ---------------- register-tiled GEMM body -> bf16 out ----------------
template<int K, bool SCALE>
__device__ __forceinline__ void gemm_body(const float* __restrict__ xin, const float* __restrict__ w,
                                          const int* __restrict__ offE, __hip_bfloat16* __restrict__ out,
                                          int blk, float* __restrict__ wl, float* __restrict__ xs) {
    int tid = threadIdx.x;
    int wv = tid >> 6, lane = tid & 63;
    int cg = lane & 15;
    int rg = lane >> 4;
    int rl = wv * 16 + rg * 4;
    int r0 = blk * 64;
    float acc[4][4] = {};
    for (int k0 = 0; k0 < K; k0 += 64) {
        {
            const float4* wsrc = (const float4*)(w + k0 * 64);
            float4* wdst = (float4*)wl;
            for (int j = tid; j < 1024; j += 256) wdst[j] = wsrc[j];
        }
        for (int p = tid; p < 1024; p += 256) {
            int r = p >> 4, c4 = p & 15;
            int row = min(r0 + r, N_NODES - 1);
            float4 vv = *(const float4*)(xin + (size_t)row * K + k0 + 4 * c4);
            *(float4*)&xs[r * 68 + 4 * c4] = vv;
        }
        __syncthreads();
#pragma unroll 4
        for (int kk = 0; kk < 64; ++kk) {
            float4 wf = *(const float4*)&wl[kk * 64 + cg * 4];
            float x0 = xs[(rl + 0) * 68 + kk];
            float x1 = xs[(rl + 1) * 68 + kk];
            float x2 = xs[(rl + 2) * 68 + kk];
            float x3 = xs[(rl + 3) * 68 + kk];
            acc[0][0] += x0 * wf.x; acc[0][1] += x0 * wf.y; acc[0][2] += x0 * wf.z; acc[0][3] += x0 * wf.w;
            acc[1][0] += x1 * wf.x; acc[1][1] += x1 * wf.y; acc[1][2] += x1 * wf.z; acc[1][3] += x1 * wf.w;
            acc[2][0] += x2 * wf.x; acc[2][1] += x2 * wf.y; acc[2][2] += x2 * wf.z; acc[2][3] += x2 * wf.w;
            acc[3][0] += x3 * wf.x; acc[3][1] += x3 * wf.y; acc[3][2] += x3 * wf.z; acc[3][3] += x3 * wf.w;
        }
        __syncthreads();
    }
#pragma unroll
    for (int i = 0; i < 4; ++i) {
        int row = r0 + rl + i;
        if (row < N_NODES) {
            float s = 1.0f;
            if (SCALE) {
                float deg = (float)(offE[row + 1] - offE[row]);
                s = rsqrtf(deg + 1.0f);
            }
            __hip_bfloat16 hv[4];
            hv[0] = __float2bfloat16(acc[i][0] * s);
            hv[1] = __float2bfloat16(acc[i][1] * s);
            hv[2] = __float2bfloat16(acc[i][2] * s);
            hv[3] = __float2bfloat16(acc[i][3] * s);
            *(ushort4*)&out[(size_t)row * 64 + cg * 4] = *(ushort4*)hv;
        }
    }
}

template<int K>
__global__ void k_gemm_dual(const float* __restrict__ in1, const float* __restrict__ w1,
                            const int* __restrict__ offE, __hip_bfloat16* __restrict__ out1,
                            const float* __restrict__ in2, const float* __restrict__ w2,
                            __hip_bfloat16* __restrict__ out2) {
    __shared__ float wl[64 * 64];
    __shared__ float xs[64 * 68];
    if (blockIdx.x < GG) gemm_body<K, true>(in1, w1, offE, out1, blockIdx.x, wl, xs);
    else                 gemm_body<K, false>(in2, w2, nullptr, out2, blockIdx.x - GG, wl, xs);
}

// ---------------- 2-wide GCN gather body, 8 loads in flight ----------------
template<bool ELU>
__device__ __forceinline__ void gcn_gather_body(const int* __restrict__ off, const int* __restrict__ srcs,
                                                const __hip_bfloat16* __restrict__ xw,
                                                const float* __restrict__ b,
                                                float* __restrict__ out, int blk) {
    int tid = threadIdx.x;
    int wv = tid >> 6, lane = tid & 63;
    int h = lane >> 5, l = lane & 31;
    int wid = blk * 4 + wv;
    if (wid >= N_NODES) return;
    int beg = off[wid];
    int cnt = off[wid + 1] - beg;
    const unsigned* xwu = (const unsigned*)xw;
    float ax0 = 0, ay0 = 0, ax1 = 0, ay1 = 0, ax2 = 0, ay2 = 0, ax3 = 0, ay3 = 0;
    int k = h;
    for (; k + 14 < cnt; k += 16) {
        int s0 = srcs[beg + k],      s1 = srcs[beg + k + 2];
        int s2 = srcs[beg + k + 4],  s3 = srcs[beg + k + 6];
        int s4 = srcs[beg + k + 8],  s5 = srcs[beg + k + 10];
        int s6 = srcs[beg + k + 12], s7 = srcs[beg + k + 14];
        unsigned v0 = xwu[(size_t)s0 * 32 + l];
        unsigned v1 = xwu[(size_t)s1 * 32 + l];
        unsigned v2 = xwu[(size_t)s2 * 32 + l];
        unsigned v3 = xwu[(size_t)s3 * 32 + l];
        unsigned v4 = xwu[(size_t)s4 * 32 + l];
        unsigned v5 = xwu[(size_t)s5 * 32 + l];
        unsigned v6 = xwu[(size_t)s6 * 32 + l];
        unsigned v7 = xwu[(size_t)s7 * 32 + l];
        ax0 += bflo(v0); ay0 += bfhi(v0);
        ax1 += bflo(v1); ay1 += bfhi(v1);
        ax2 += bflo(v2); ay2 += bfhi(v2);
        ax3 += bflo(v3); ay3 += bfhi(v3);
        ax0 += bflo(v4); ay0 += bfhi(v4);
        ax1 += bflo(v5); ay1 += bfhi(v5);
        ax2 += bflo(v6); ay2 += bfhi(v6);
        ax3 += bflo(v7); ay3 += bfhi(v7);
    }
    for (; k + 6 < cnt; k += 8) {
        int s0 = srcs[beg + k],     s1 = srcs[beg + k + 2];
        int s2 = srcs[beg + k + 4], s3 = srcs[beg + k + 6];
        unsigned v0 = xwu[(size_t)s0 * 32 + l];
        unsigned v1 = xwu[(size_t)s1 * 32 + l];
        unsigned v2 = xwu[(size_t)s2 * 32 + l];
        unsigned v3 = xwu[(size_t)s3 * 32 + l];
        ax0 += bflo(v0); ay0 += bfhi(v0);
        ax1 += bflo(v1); ay1 += bfhi(v1);
        ax2 += bflo(v2); ay2 += bfhi(v2);
        ax3 += bflo(v3); ay3 += bfhi(v3);
    }
    for (; k < cnt; k += 2) {
        unsigned v = xwu[(size_t)srcs[beg + k] * 32 + l];
        ax0 += bflo(v); ay0 += bfhi(v);
    }
    float tx = (ax0 + ax1) + (ax2 + ax3);
    float ty = (ay0 + ay1) + (ay2 + ay3);
    tx += __shfl_xor(tx, 32);
    ty += __shfl_xor(ty, 32);
    unsigned sv = xwu[(size_t)wid * 32 + l];
    float di = rsqrtf((float)cnt + 1.0f);
    float vx = di * (tx + bflo(sv)) + b[2 * l];
    float vy = di * (ty + bfhi(sv)) + b[2 * l + 1];
    if (ELU) {
        vx = (vx > 0.0f) ? vx : expm1f(vx);
        vy = (vy > 0.0f) ? vy : expm1f(vy);
    }
    if (h == 0) *(float2*)(out + (size_t)wid * 64 + 2 * l) = make_float2(vx, vy);
}

// ---------------- 2-wide hyperedge gather body, 8 loads in flight ----------------
__device__ __forceinline__ void he_gather_body(const int* __restrict__ off, const int* __restrict__ nodes,
                                               const __hip_bfloat16* __restrict__ xw,
                                               float* __restrict__ C, int he, float2 (*red)[32]) {
    int tid = threadIdx.x;
    int wv = tid >> 6, lane = tid & 63;
    int h = lane >> 5, l = lane & 31;
    int beg = off[he], end = off[he + 1];
    int cnt = end - beg;
    int per = (cnt + 3) >> 2;
    int b0 = beg + wv * per;
    int e0 = min(b0 + per, end);
    int c2 = e0 - b0;
    const unsigned* xwu = (const unsigned*)xw;
    float ax0 = 0, ay0 = 0, ax1 = 0, ay1 = 0, ax2 = 0, ay2 = 0, ax3 = 0, ay3 = 0;
    int k = h;
    for (; k + 14 < c2; k += 16) {
        int s0 = nodes[b0 + k],      s1 = nodes[b0 + k + 2];
        int s2 = nodes[b0 + k + 4],  s3 = nodes[b0 + k + 6];
        int s4 = nodes[b0 + k + 8],  s5 = nodes[b0 + k + 10];
        int s6 = nodes[b0 + k + 12], s7 = nodes[b0 + k + 14];
        unsigned v0 = xwu[(size_t)s0 * 32 + l];
        unsigned v1 = xwu[(size_t)s1 * 32 + l];
        unsigned v2 = xwu[(size_t)s2 * 32 + l];
        unsigned v3 = xwu[(size_t)s3 * 32 + l];
        unsigned v4 = xwu[(size_t)s4 * 32 + l];
        unsigned v5 = xwu[(size_t)s5 * 32 + l];
        unsigned v6 = xwu[(size_t)s6 * 32 + l];
        unsigned v7 = xwu[(size_t)s7 * 32 + l];
        ax0 += bflo(v0); ay0 += bfhi(v0);
        ax1 += bflo(v1); ay1 += bfhi(v1);
        ax2 += bflo(v2); ay2 += bfhi(v2);
        ax3 += bflo(v3); ay3 += bfhi(v3);
        ax0 += bflo(v4); ay0 += bfhi(v4);
        ax1 += bflo(v5); ay1 += bfhi(v5);
        ax2 += bflo(v6); ay2 += bfhi(v6);
        ax3 += bflo(v7); ay3 += bfhi(v7);
    }
    for (; k + 6 < c2; k += 8) {
        int s0 = nodes[b0 + k],     s1 = nodes[b0 + k + 2];
        int s2 = nodes[b0 + k + 4], s3 = nodes[b0 + k + 6];
        unsigned v0 = xwu[(size_t)s0 * 32 + l];
        unsigned v1 = xwu[(size_t)s1 * 32 + l];
        unsigned v2 = xwu[(size_t)s2 * 32 + l];
        unsigned v3 = xwu[(size_t)s3 * 32 + l];
        ax0 += bflo(v0); ay0 += bfhi(v0);
        ax1 += bflo(v1); ay1 += bfhi(v1);
        ax2 += bflo(v2); ay2 += bfhi(v2);
        ax3 += bflo(v3); ay3 += bfhi(v3);
    }
    for (; k < c2; k += 2) {
        unsigned v = xwu[(size_t)nodes[b0 + k] * 32 + l];
        ax0 += bflo(v); ay0 += bfhi(v);
    }
    float tx = (ax0 + ax1) + (ax2 + ax3);
    float ty = (ay0 + ay1) + (ay2 + ay3);
    tx += __shfl_xor(tx, 32);
    ty += __shfl_xor(ty, 32);
    if (h == 0) red[wv][l] = make_float2(tx, ty);
    __syncthreads();
    if (tid < 32) {
        float2 r0 = red[0][tid], r1 = red[1][tid], r2 = red[2][tid], r3 = red[3][tid];
        float binv = (cnt > 0) ? 1.0f / (float)cnt : 0.0f;
        float2 o = make_float2((r0.x + r1.x + r2.x + r3.x) * binv,
                               (r0.y + r1.y + r2.y + r3.y) * binv);
        *(float2*)(C + (size_t)he * 64 + 2 * tid) = o;
    }
}

template<bool ELU>
__global__ __launch_bounds__(256, 6)
void k_gather_dual(const int* __restrict__ offE, const int* __restrict__ srtE,
                   const __hip_bfloat16* __restrict__ A, const float* __restrict__ gb,
                   float* __restrict__ aggOut,
                   const int* __restrict__ offH, const int* __restrict__ srtH,
                   const __hip_bfloat16* __restrict__ B, float* __restrict__ C) {
    __shared__ float2 red[4][32];
    if (blockIdx.x < GWN) gcn_gather_body<ELU>(offE, srtE, A, gb, aggOut, blockIdx.x);
    else                  he_gather_body(offH, srtH, B, C, blockIdx.x - GWN, red);
}

// ---------------- 2-wide node gather (fp32 C in): Dinv+bias+ELU (+gating) ----------------
template<bool ELU, bool FUSE>
__global__ __launch_bounds__(256, 8)
void k_node_gather(const int* __restrict__ off, const int* __restrict__ hes,
                   const float* __restrict__ C, const float* __restrict__ b,
                   float* __restrict__ out,
                   const float* __restrict__ xs, const float* __restrict__ gate,
                   float* __restrict__ z) {
    int tid = threadIdx.x;
    int wv = tid >> 6, lane = tid & 63;
    int h = lane >> 5, l = lane & 31;
    int wid = blockIdx.x * 4 + wv;
    if (wid >= N_NODES) return;
    int beg = off[wid];
    int cnt = off[wid + 1] - beg;
    float ax0 = 0, ay0 = 0, ax1 = 0, ay1 = 0, ax2 = 0, ay2 = 0, ax3 = 0, ay3 = 0;
    int k = h;
    for (; k + 6 < cnt; k += 8) {
        float2 c0 = *(const float2*)(C + (size_t)hes[beg + k] * 64 + 2 * l);
        float2 c1 = *(const float2*)(C + (size_t)hes[beg + k + 2] * 64 + 2 * l);
        float2 c2 = *(const float2*)(C + (size_t)hes[beg + k + 4] * 64 + 2 * l);
        float2 c3 = *(const float2*)(C + (size_t)hes[beg + k + 6] * 64 + 2 * l);
        ax0 += c0.x; ay0 += c0.y;
        ax1 += c1.x; ay1 += c1.y;
        ax2 += c2.x; ay2 += c2.y;
        ax3 += c3.x; ay3 += c3.y;
    }
    for (; k < cnt; k += 2) {
        float2 c = *(const float2*)(C + (size_t)hes[beg + k] * 64 + 2 * l);
        ax0 += c.x; ay0 += c.y;
    }
    float tx = (ax0 + ax1) + (ax2 + ax3);
    float ty = (ay0 + ay1) + (ay2 + ay3);
    tx += __shfl_xor(tx, 32);
    ty += __shfl_xor(ty, 32);
    float dinv = (cnt > 0) ? 1.0f / (float)cnt : 0.0f;
    float vx = dinv * tx + b[2 * l];
    float vy = dinv * ty + b[2 * l + 1];
    if (ELU) {
        vx = (vx > 0.0f) ? vx : expm1f(vx);
        vy = (vy > 0.0f) ? vy : expm1f(vy);
    }
    if (h == 0) {
        size_t idx = (size_t)wid * 64 + 2 * l;
        *(float2*)(out + idx) = make_float2(vx, vy);
        if (FUSE) {
            float a = 1.0f / (1.0f + expf(-gate[0]));
            float2 s = *(const float2*)(xs + idx);
            *(float2*)(z + idx) = make_float2(a * s.x + (1.0f - a) * vx,
                                              a * s.y + (1.0f - a) * vy);
        }
    }
}

extern "C" void kernel_launch(void* const* d_in, const int* in_sizes, int n_in,
                              void* d_out, int out_size, void* d_ws, size_t ws_size,
                              hipStream_t stream) {
    const float* x      = (const float*)d_in[0];
    const int*   ei     = (const int*)d_in[1];
    const int*   hei    = (const int*)d_in[2];
    const float* gcn1_w = (const float*)d_in[3];
    const float* gcn1_b = (const float*)d_in[4];
    const float* gcn2_w = (const float*)d_in[5];
    const float* gcn2_b = (const float*)d_in[6];
    const float* hyp1_w = (const float*)d_in[7];
    const float* hyp1_b = (const float*)d_in[8];
    const float* hyp2_w = (const float*)d_in[9];
    const float* hyp2_b = (const float*)d_in[10];
    const float* gate   = (const float*)d_in[11];
    float* out = (float*)d_out;

    const int* e_row = ei;
    const int* e_col = ei + N_EDGES;
    const int* n_idx = hei;
    const int* h_idx = hei + NNZ_H;

    const size_t NV = (size_t)N_NODES * 64;
    float* z_out  = out;
    float* xs_out = out + NV;
    float* xd_out = out + 2 * NV;

    // ---- workspace layout ----
    char* base = (char*)d_ws;
    __hip_bfloat16* Abf = (__hip_bfloat16*)base;            // 6.4 MB
    __hip_bfloat16* Bbf = (__hip_bfloat16*)(base + NV * 2); // 6.4 MB
    float* AGG1 = (float*)(base + NV * 4);                  // 12.8 MB
    float* AGG2 = (float*)(base + NV * 8);                  // 12.8 MB
    float* C    = (float*)(base + NV * 12);                 // 2.56 MB
    int* srtE = (int*)(C + (size_t)M_HE * 64);
    int* srtH = srtE + N_EDGES;
    int* srtN = srtH + NNZ_H;
    int* offE = srtN + NNZ_H;
    int* offH = offE + (N_NODES + 1);
    int* offN = offH + (M_HE + 1);
    int* bcntE = offN + (N_NODES + 1);
    int* bcntH = bcntE + NB_E;
    int* bcntN = bcntH + NB_H;
    int* bcurE = bcntN + NB_N;
    int* bcurH = bcurE + NB_E;
    int* bcurN = bcurH + NB_H;
    const size_t zero_ints = 2 * (size_t)(NB_E + NB_H + NB_N);
    int* bkE = (int*)Abf;
    int* bkH = (int*)Bbf;
    int* bkN = (int*)AGG1;

    const int BLK = 256;

    // ---- CSR build (3 launches) ----
    hipMemsetAsync(bcntE, 0, zero_ints * sizeof(int), stream);
    k_hist_all<<<256, BLK, 0, stream>>>(e_col, h_idx, n_idx, bcntE, bcntH, bcntN);
    k_chunk_all<<<3 * GB, BLK, 0, stream>>>(e_row, e_col, n_idx, h_idx,
                                            bcntE, bcurE, bkE,
                                            bcntH, bcurH, bkH,
                                            bcntN, bcurN, bkN);
    k_fin_all<<<NB_E + NB_H + NB_N, BLK, 0, stream>>>(bkE, bcntE, srtE, offE,
                                                      bkH, bcntH, srtH, offH,
                                                      bkN, bcntN, srtN, offN);

    // ---- G13: Abf = dis.*(x@w1)  ||  Bbf = x@hw1 ----
    k_gemm_dual<F_IN><<<2 * GG, BLK, 0, stream>>>(x, gcn1_w, offE, Abf, x, hyp1_w, Bbf);
    // ---- DG1: AGG1 = ELU(gcnGather(Abf))  ||  C = heGather(Bbf) ----
    k_gather_dual<true><<<GWN + M_HE, BLK, 0, stream>>>(offE, srtE, Abf, gcn1_b, AGG1,
                                                        offH, srtH, Bbf, C);
    // ---- nodeG1: AGG2 = ELU(Dinv*(H C) + hb1) ----
    k_node_gather<true, false><<<GWN, BLK, 0, stream>>>(offN, srtN, C, hyp1_b, AGG2,
                                                        nullptr, nullptr, nullptr);
    // ---- G24: Abf = dis.*(AGG1@w2)  ||  Bbf = AGG2@hw2 ----
    k_gemm_dual<F_HID><<<2 * GG, BLK, 0, stream>>>(AGG1, gcn2_w, offE, Abf, AGG2, hyp2_w, Bbf);
    // ---- DG2: xs_out = gcnGather(Abf)  ||  C = heGather(Bbf) ----
    k_gather_dual<false><<<GWN + M_HE, BLK, 0, stream>>>(offE, srtE, Abf, gcn2_b, xs_out,
                                                         offH, srtH, Bbf, C);
    // ---- nodeG2 + gating ----
    k_node_gather<false, true><<<GWN, BLK, 0, stream>>>(offN, srtN, C, hyp2_b, xd_out,
                                                        xs_out, gate, z_out);

    (void)in_sizes; (void)n_in; (void)out_size; (void)ws_size;
}